// Round 5
// baseline (624.647 us; speedup 1.0000x reference)
//
#include <hip/hip_runtime.h>
#include <math.h>

#define BB 8
#define SS 1024
#define DD 512
#define HH 8
#define NROWS (BB*SS)          // 8192
#define EPSV 1e-5f
#define SCALE_V 0.125f          // 1/sqrt(64)

// stats[] layout (floats)
#define I_SUM1 0
#define I_SS1  8
#define I_CNT  16
#define I_MEAN1 24
#define I_INV1 32
#define I_SUM2 40
#define I_SS2  48
#define I_MEAN2 56
#define I_INV2 64
// int region (indices into (int*)stats)
#define I_TMASK 96              // 128 per-64-row-tile valid flags
#define I_KBITS 224             // 8 per-batch 16-bit tile masks

typedef __bf16 bf16x8 __attribute__((ext_vector_type(8)));
typedef __bf16 bf16x4 __attribute__((ext_vector_type(4)));
typedef float f32x4 __attribute__((ext_vector_type(4)));

#define MFMA16(a,b,c) __builtin_amdgcn_mfma_f32_16x16x32_bf16(a,b,c,0,0,0)

// GEMM LDS tiles: 64 rows x 32 k bf16, padded stride 40 (2-way bank alias = free)
#define LDSTRIDE 40
// attention K/V staging tiles: 64 rows x 64 k bf16, padded stride 72
#define ASTR 72

// ---------------- stats pass 1: fmask + masked sum/sumsq per batch ----------
__global__ __launch_bounds__(128) void stats1_k(const float* __restrict__ Q,
                                                float* __restrict__ fmask,
                                                float* __restrict__ stats) {
    int row = blockIdx.x;
    int b = row >> 10;
    int t = threadIdx.x;
    float4 v = *(const float4*)(Q + ((size_t)row << 9) + (t << 2));
    float s  = v.x + v.y + v.z + v.w;
    float ss = v.x*v.x + v.y*v.y + v.z*v.z + v.w*v.w;
    int nz = (v.x != 0.f) || (v.y != 0.f) || (v.z != 0.f) || (v.w != 0.f);
    __shared__ float rs[128], rss[128];
    __shared__ int rnz[128];
    rs[t] = s; rss[t] = ss; rnz[t] = nz;
    __syncthreads();
    for (int off = 64; off > 0; off >>= 1) {
        if (t < off) { rs[t] += rs[t+off]; rss[t] += rss[t+off]; rnz[t] |= rnz[t+off]; }
        __syncthreads();
    }
    if (t == 0) {
        float f = rnz[0] ? 1.f : 0.f;
        fmask[row] = f;
        if (f != 0.f) {
            atomicAdd(&stats[I_SUM1 + b], rs[0]);
            atomicAdd(&stats[I_SS1 + b], rss[0]);
            atomicAdd(&stats[I_CNT + b], 1.f);
        }
    }
}

// ---------------- finalize: mean/inv (+ tile masks on pass 1) ---------------
__global__ __launch_bounds__(128) void finalize_k(float* __restrict__ stats,
                                                  const float* __restrict__ fmask,
                                                  int osum, int oss, int ocnt,
                                                  int omean, int oinv, int dotile) {
    int t = threadIdx.x;
    if (t < BB) {
        float cntD = stats[ocnt + t] * 512.f;
        float mean = stats[osum + t] / cntD;
        float var  = stats[oss + t] / cntD - mean * mean;
        stats[omean + t] = mean;
        stats[oinv + t]  = rsqrtf(var + EPSV);
    }
    if (dotile) {
        int* ip = (int*)stats;
        const float* fr = fmask + (t << 6);
        int any = 0;
        for (int i = 0; i < 64; i += 4) {
            float4 v = *(const float4*)(fr + i);
            any |= (v.x != 0.f) | (v.y != 0.f) | (v.z != 0.f) | (v.w != 0.f);
        }
        ip[I_TMASK + t] = any;
        __syncthreads();
        if (t < BB) {
            int bits = 0;
            #pragma unroll
            for (int i = 0; i < 16; ++i)
                bits |= (ip[I_TMASK + (t << 4) + i] ? 1 : 0) << i;
            ip[I_KBITS + t] = bits;
        }
    }
}

// ---------------- transpose+cast weights: W[k][n] fp32 -> Wt[n][k] bf16 -----
__global__ __launch_bounds__(256) void tw_k(const float* __restrict__ Wq,
                                            const float* __restrict__ Wk,
                                            const float* __restrict__ Wv,
                                            const float* __restrict__ Wo,
                                            __bf16* __restrict__ Wt) {
    int z = blockIdx.z;
    const float* W = (z == 0) ? Wq : (z == 1) ? Wk : (z == 2) ? Wv : Wo;
    __bf16* dst = Wt + ((size_t)z << 18);
    __shared__ float tile[64][65];
    int t = threadIdx.x;
    int k0 = blockIdx.y << 6, n0 = blockIdx.x << 6;
    int r = t >> 4, c = (t & 15) << 2;
    #pragma unroll
    for (int i = 0; i < 4; ++i) {
        float4 v = *(const float4*)(W + (size_t)(k0 + r + i*16) * 512 + n0 + c);
        tile[r + i*16][c+0] = v.x; tile[r + i*16][c+1] = v.y;
        tile[r + i*16][c+2] = v.z; tile[r + i*16][c+3] = v.w;
    }
    __syncthreads();
    #pragma unroll
    for (int i = 0; i < 4; ++i) {
        int n = r + i*16;
        bf16x4 o;
        o[0] = (__bf16)tile[c+0][n]; o[1] = (__bf16)tile[c+1][n];
        o[2] = (__bf16)tile[c+2][n]; o[3] = (__bf16)tile[c+3][n];
        *(bf16x4*)(dst + (size_t)(n0 + n) * 512 + k0 + c) = o;
    }
}

// ---------------- fused set_norm + QKV projection (single pass over Q) ------
__global__ __launch_bounds__(256) void projqkv_k(
    const float* __restrict__ Q, const float* __restrict__ stats,
    const float* __restrict__ fmask, const __bf16* __restrict__ Wt,
    const float* __restrict__ bq, const float* __restrict__ bk,
    const float* __restrict__ bv,
    __bf16* __restrict__ Qp, __bf16* __restrict__ Kp, __bf16* __restrict__ Vt)
{
    __shared__ __align__(16) __bf16 smem[64 * LDSTRIDE * 4];   // As + 3x Bs
    int t = threadIdx.x;
    int m0 = blockIdx.y << 6, n0 = blockIdx.x << 6;
    int b = m0 >> 10, s0 = m0 & 1023, h = n0 >> 6;
    int bh = (b << 3) + h;
    const int* ip = (const int*)stats;
    if (!ip[I_TMASK + (m0 >> 6)]) {
        int m = t >> 2, ch = (t & 3) << 4;
        bf16x8 z = {};
        *(bf16x8*)(Qp + ((size_t)(m0 + m) << 9) + n0 + ch)     = z;
        *(bf16x8*)(Qp + ((size_t)(m0 + m) << 9) + n0 + ch + 8) = z;
        *(bf16x8*)(Kp + ((size_t)(m0 + m) << 9) + n0 + ch)     = z;
        *(bf16x8*)(Kp + ((size_t)(m0 + m) << 9) + n0 + ch + 8) = z;
        *(bf16x8*)(Vt + ((size_t)bh << 16) + ((size_t)m << 10) + s0 + ch)     = z;
        *(bf16x8*)(Vt + ((size_t)bh << 16) + ((size_t)m << 10) + s0 + ch + 8) = z;
        return;
    }
    __bf16* As = smem;
    int srow = t >> 2, skp = (t & 3) << 3;
    int arow = m0 + srow;
    float fi   = fmask[arow] * stats[I_INV1 + b];
    float mean = stats[I_MEAN1 + b];
    int wave = t >> 6, lane = t & 63, quad = lane >> 4, l16 = lane & 15;
    int aoff  = (wave * 16 + l16) * LDSTRIDE + quad * 8;
    int boff0 = l16 * LDSTRIDE + quad * 8;
    f32x4 acc[3][4] = {};
    const float*  Arow = Q + ((size_t)arow << 9);
    const __bf16* Brow = Wt + ((size_t)(n0 + srow) << 9);
    float4 a0 = *(const float4*)(Arow + skp);
    float4 a1 = *(const float4*)(Arow + skp + 4);
    bf16x8 w0 = *(const bf16x8*)(Brow + skp);
    bf16x8 w1 = *(const bf16x8*)(Brow + (1 << 18) + skp);
    bf16x8 w2 = *(const bf16x8*)(Brow + (2 << 18) + skp);
    for (int k0 = 0; k0 < 512; k0 += 32) {
        bf16x8 av;
        av[0] = (__bf16)((a0.x - mean) * fi); av[1] = (__bf16)((a0.y - mean) * fi);
        av[2] = (__bf16)((a0.z - mean) * fi); av[3] = (__bf16)((a0.w - mean) * fi);
        av[4] = (__bf16)((a1.x - mean) * fi); av[5] = (__bf16)((a1.y - mean) * fi);
        av[6] = (__bf16)((a1.z - mean) * fi); av[7] = (__bf16)((a1.w - mean) * fi);
        *(bf16x8*)&As[srow * LDSTRIDE + skp] = av;
        *(bf16x8*)&smem[64*LDSTRIDE*1 + srow * LDSTRIDE + skp] = w0;
        *(bf16x8*)&smem[64*LDSTRIDE*2 + srow * LDSTRIDE + skp] = w1;
        *(bf16x8*)&smem[64*LDSTRIDE*3 + srow * LDSTRIDE + skp] = w2;
        __syncthreads();
        if (k0 < 480) {
            a0 = *(const float4*)(Arow + k0 + 32 + skp);
            a1 = *(const float4*)(Arow + k0 + 36 + skp);
            w0 = *(const bf16x8*)(Brow + k0 + 32 + skp);
            w1 = *(const bf16x8*)(Brow + (1 << 18) + k0 + 32 + skp);
            w2 = *(const bf16x8*)(Brow + (2 << 18) + k0 + 32 + skp);
        }
        bf16x8 af = *(const bf16x8*)&As[aoff];
        #pragma unroll
        for (int nt = 0; nt < 4; ++nt) {
            int bo = boff0 + nt * (16 * LDSTRIDE);
            acc[0][nt] = MFMA16(af, *(const bf16x8*)&smem[64*LDSTRIDE*1 + bo], acc[0][nt]);
            acc[1][nt] = MFMA16(af, *(const bf16x8*)&smem[64*LDSTRIDE*2 + bo], acc[1][nt]);
            acc[2][nt] = MFMA16(af, *(const bf16x8*)&smem[64*LDSTRIDE*3 + bo], acc[2][nt]);
        }
        __syncthreads();
    }
    float fmr[4];
    #pragma unroll
    for (int reg = 0; reg < 4; ++reg) fmr[reg] = fmask[m0 + wave*16 + quad*4 + reg];
    __bf16* Cs = smem;    // reuse; safe after final loop barrier
    #pragma unroll
    for (int z = 0; z < 2; ++z) {
        const float* bias = z ? bk : bq;
        __bf16* C = z ? Kp : Qp;
        #pragma unroll
        for (int nt = 0; nt < 4; ++nt) {
            float bn = bias[n0 + nt * 16 + l16];
            #pragma unroll
            for (int reg = 0; reg < 4; ++reg) {
                int m = wave * 16 + quad * 4 + reg;
                Cs[m * 70 + nt * 16 + l16] = (__bf16)((acc[z][nt][reg] + bn) * fmr[reg]);
            }
        }
        __syncthreads();
        int m = t >> 2, ch = (t & 3) << 4;
        bf16x8 o0 = *(const bf16x8*)&Cs[m * 70 + ch];
        bf16x8 o1 = *(const bf16x8*)&Cs[m * 70 + ch + 8];
        *(bf16x8*)(C + ((size_t)(m0 + m) << 9) + n0 + ch)     = o0;
        *(bf16x8*)(C + ((size_t)(m0 + m) << 9) + n0 + ch + 8) = o1;
        __syncthreads();
    }
    #pragma unroll
    for (int nt = 0; nt < 4; ++nt) {
        int d = nt * 16 + l16;
        float bn = bv[n0 + d];
        #pragma unroll
        for (int reg = 0; reg < 4; ++reg) {
            int sl = wave * 16 + quad * 4 + reg;
            Cs[d * 70 + sl] = (__bf16)((acc[2][nt][reg] + bn) * fmr[reg]);
        }
    }
    __syncthreads();
    {
        int d = t >> 2, seg = (t & 3) << 4;
        bf16x8 o0 = *(const bf16x8*)&Cs[d * 70 + seg];
        bf16x8 o1 = *(const bf16x8*)&Cs[d * 70 + seg + 8];
        *(bf16x8*)(Vt + ((size_t)bh << 16) + ((size_t)d << 10) + s0 + seg)     = o0;
        *(bf16x8*)(Vt + ((size_t)bh << 16) + ((size_t)d << 10) + s0 + seg + 8) = o1;
    }
}

// ---------------- fused attention, QBLK=128, dbuf K/V, wave-private Ws ------
// grid (8, 64), 256 threads. Each wave owns 32 q-rows (two 16-row groups).
// Phase A: row sums, K double-buffered (KsA/KsB), 1 barrier/tile.
// Phase B: QK^T -> Ws (wave-private, NO barriers) -> PV + w store,
//          K/V double-buffered, 1 barrier/tile. Barrier precedes the reg
//          prefetch so the vmcnt(0) barrier-drain hits already-complete loads.
__global__ __launch_bounds__(256) void attn_k(
    const __bf16* __restrict__ Qp, const __bf16* __restrict__ Kp,
    const __bf16* __restrict__ Vt,
    const float* __restrict__ fmask, const float* __restrict__ Q,
    float* __restrict__ stats, float* __restrict__ w, float* __restrict__ attn)
{
    int bh = blockIdx.y, b = bh >> 3, h = bh & 7;
    int q0 = blockIdx.x << 7;
    int t = threadIdx.x;
    const int* ip = (const int*)stats;
    int kb = ip[I_KBITS + b];
    int fb = b << 10;
    size_t wqbase = ((size_t)bh << 20) + ((size_t)q0 << 10);
    int qt0 = q0 >> 6;
    if (!(((kb >> qt0) & 1) || ((kb >> (qt0 + 1)) & 1))) {
        // both 64-row subtiles masked: w rows = 0, attn = Q
        int rr = t >> 2, ch = (t & 3) << 4;
        float4 z4 = {0.f, 0.f, 0.f, 0.f};
        #pragma unroll
        for (int rb = 0; rb < 128; rb += 64) {
            float* wp0 = w + wqbase + ((size_t)(rb + rr) << 10) + ch;
            #pragma unroll
            for (int kc0 = 0; kc0 < 1024; kc0 += 64) {
                *(float4*)(wp0 + kc0)      = z4;
                *(float4*)(wp0 + kc0 + 4)  = z4;
                *(float4*)(wp0 + kc0 + 8)  = z4;
                *(float4*)(wp0 + kc0 + 12) = z4;
            }
            size_t base = ((size_t)(fb + q0 + rb + rr) << 9) + (h << 6) + ch;
            #pragma unroll
            for (int i = 0; i < 4; ++i)
                *(float4*)(attn + base + i*4) = *(const float4*)(Q + base + i*4);
        }
        return;
    }
    __shared__ __align__(16) __bf16 KsA[64 * ASTR];
    __shared__ __align__(16) __bf16 KsB[64 * ASTR];
    __shared__ __align__(16) __bf16 VsA[64 * ASTR];
    __shared__ __align__(16) __bf16 VsB[64 * ASTR];
    __shared__ __align__(16) __bf16 Ws[128 * ASTR];
    __shared__ float red[8];
    int wave = t >> 6, lane = t & 63, quad = lane >> 4, l16 = lane & 15;
    int sr = t >> 3, sc = (t & 7) << 3;
    // Q fragments: one-time gather for both 16-row groups
    bf16x8 qa[2][2];
    #pragma unroll
    for (int g = 0; g < 2; ++g) {
        const __bf16* Qr = Qp + ((size_t)(fb + q0 + wave*32 + g*16 + l16) << 9) + (h << 6) + (quad << 3);
        qa[g][0] = *(const bf16x8*)(Qr);
        qa[g][1] = *(const bf16x8*)(Qr + 32);
    }

    // ---- phase A: row sums (K dbuf, 1 barrier/tile) ----
    float rsum[2][4] = {};
    bf16x8 kr0, kr1, vr0, vr1;
    bool curok = kb & 1;
    if (curok) {
        kr0 = *(const bf16x8*)(Kp + ((size_t)(fb + sr) << 9) + (h << 6) + sc);
        kr1 = *(const bf16x8*)(Kp + ((size_t)(fb + 32 + sr) << 9) + (h << 6) + sc);
    }
    int ai = 0;
    for (int kc = 0; kc < 16; ++kc) {
        bool nextok = (kc < 15) && ((kb >> (kc + 1)) & 1);
        int nb = fb + ((kc + 1) << 6);
        if (curok) {
            __bf16* Kd = (ai & 1) ? KsB : KsA;
            *(bf16x8*)&Kd[sr * ASTR + sc] = kr0;
            *(bf16x8*)&Kd[(32 + sr) * ASTR + sc] = kr1;
            __syncthreads();
            if (nextok) {
                kr0 = *(const bf16x8*)(Kp + ((size_t)(nb + sr) << 9) + (h << 6) + sc);
                kr1 = *(const bf16x8*)(Kp + ((size_t)(nb + 32 + sr) << 9) + (h << 6) + sc);
            }
            int kc0 = kc << 6;
            #pragma unroll
            for (int nt = 0; nt < 4; ++nt) {
                int boff = (nt * 16 + l16) * ASTR + (quad << 3);
                bf16x8 kf0 = *(const bf16x8*)&Kd[boff];
                bf16x8 kf1 = *(const bf16x8*)&Kd[boff + 32];
                float fk = fmask[fb + kc0 + nt * 16 + l16];
                #pragma unroll
                for (int g = 0; g < 2; ++g) {
                    f32x4 s = {};
                    s = MFMA16(qa[g][0], kf0, s);
                    s = MFMA16(qa[g][1], kf1, s);
                    #pragma unroll
                    for (int r = 0; r < 4; ++r)
                        rsum[g][r] += (fk != 0.f) ? __expf(s[r] * SCALE_V) : 0.f;
                }
            }
            ++ai;
        } else if (nextok) {
            kr0 = *(const bf16x8*)(Kp + ((size_t)(nb + sr) << 9) + (h << 6) + sc);
            kr1 = *(const bf16x8*)(Kp + ((size_t)(nb + 32 + sr) << 9) + (h << 6) + sc);
        }
        curok = nextok;
    }
    float inv[2][4];
    #pragma unroll
    for (int g = 0; g < 2; ++g)
        #pragma unroll
        for (int r = 0; r < 4; ++r) {
            float v = rsum[g][r];
            v += __shfl_xor(v, 1); v += __shfl_xor(v, 2);
            v += __shfl_xor(v, 4); v += __shfl_xor(v, 8);
            float fq = fmask[fb + q0 + wave*32 + g*16 + quad*4 + r];
            inv[g][r] = (fq != 0.f && v > 0.f) ? 1.f / v : 0.f;
        }
    __syncthreads();   // phase-A LDS reads drained before phase-B staging

    // ---- phase B: attention (K/V dbuf, 1 barrier/tile) ----
    f32x4 accO[2][4] = {};
    curok = kb & 1;
    if (curok) {
        kr0 = *(const bf16x8*)(Kp + ((size_t)(fb + sr) << 9) + (h << 6) + sc);
        kr1 = *(const bf16x8*)(Kp + ((size_t)(fb + 32 + sr) << 9) + (h << 6) + sc);
        vr0 = *(const bf16x8*)(Vt + ((size_t)bh << 16) + ((size_t)sr << 10) + sc);
        vr1 = *(const bf16x8*)(Vt + ((size_t)bh << 16) + ((size_t)(32 + sr) << 10) + sc);
    }
    ai = 0;
    for (int kc = 0; kc < 16; ++kc) {
        int kc0 = kc << 6;
        bool nextok = (kc < 15) && ((kb >> (kc + 1)) & 1);
        int nk0 = kc0 + 64;
        if (curok) {
            __bf16* Kd = (ai & 1) ? KsB : KsA;
            __bf16* Vd = (ai & 1) ? VsB : VsA;
            *(bf16x8*)&Kd[sr * ASTR + sc] = kr0;
            *(bf16x8*)&Kd[(32 + sr) * ASTR + sc] = kr1;
            *(bf16x8*)&Vd[sr * ASTR + sc] = vr0;
            *(bf16x8*)&Vd[(32 + sr) * ASTR + sc] = vr1;
            __syncthreads();
            if (nextok) {   // issue after barrier; completes under compute below
                kr0 = *(const bf16x8*)(Kp + ((size_t)(fb + nk0 + sr) << 9) + (h << 6) + sc);
                kr1 = *(const bf16x8*)(Kp + ((size_t)(fb + nk0 + 32 + sr) << 9) + (h << 6) + sc);
                vr0 = *(const bf16x8*)(Vt + ((size_t)bh << 16) + ((size_t)sr << 10) + nk0 + sc);
                vr1 = *(const bf16x8*)(Vt + ((size_t)bh << 16) + ((size_t)(32 + sr) << 10) + nk0 + sc);
            }
            // QK^T -> p (normalized) -> Ws (wave-private rows, no barrier)
            #pragma unroll
            for (int nt = 0; nt < 4; ++nt) {
                int boff = (nt * 16 + l16) * ASTR + (quad << 3);
                bf16x8 kf0 = *(const bf16x8*)&Kd[boff];
                bf16x8 kf1 = *(const bf16x8*)&Kd[boff + 32];
                float fk = fmask[fb + kc0 + nt * 16 + l16];
                #pragma unroll
                for (int g = 0; g < 2; ++g) {
                    f32x4 s = {};
                    s = MFMA16(qa[g][0], kf0, s);
                    s = MFMA16(qa[g][1], kf1, s);
                    #pragma unroll
                    for (int r = 0; r < 4; ++r) {
                        float p = (fk != 0.f) ? __expf(s[r] * SCALE_V) * inv[g][r] : 0.f;
                        Ws[(wave*32 + g*16 + quad*4 + r) * ASTR + nt*16 + l16] = (__bf16)p;
                    }
                }
            }
            // PV: A-frags from own Ws rows (lgkmcnt-ordered), B-frags from Vd
            #pragma unroll
            for (int g = 0; g < 2; ++g) {
                int prow = wave*32 + g*16 + l16;
                bf16x8 pa0 = *(const bf16x8*)&Ws[prow * ASTR + (quad << 3)];
                bf16x8 pa1 = *(const bf16x8*)&Ws[prow * ASTR + 32 + (quad << 3)];
                #pragma unroll
                for (int nt2 = 0; nt2 < 4; ++nt2) {
                    int voff = (nt2 * 16 + l16) * ASTR + (quad << 3);
                    accO[g][nt2] = MFMA16(pa0, *(const bf16x8*)&Vd[voff], accO[g][nt2]);
                    accO[g][nt2] = MFMA16(pa1, *(const bf16x8*)&Vd[voff + 32], accO[g][nt2]);
                }
            }
            // w store from own Ws rows (row = t>>1 in [32*wave, 32*wave+32))
            {
                int row = t >> 1, ch = (t & 1) << 5;
                float* wp = w + wqbase + ((size_t)row << 10) + kc0 + ch;
                #pragma unroll
                for (int jj = 0; jj < 2; ++jj) {
                    bf16x8 p0 = *(const bf16x8*)&Ws[row * ASTR + ch + jj*16];
                    bf16x8 p1 = *(const bf16x8*)&Ws[row * ASTR + ch + jj*16 + 8];
                    float4 f0, f1, f2, f3;
                    f0.x = (float)p0[0]; f0.y = (float)p0[1]; f0.z = (float)p0[2]; f0.w = (float)p0[3];
                    f1.x = (float)p0[4]; f1.y = (float)p0[5]; f1.z = (float)p0[6]; f1.w = (float)p0[7];
                    f2.x = (float)p1[0]; f2.y = (float)p1[1]; f2.z = (float)p1[2]; f2.w = (float)p1[3];
                    f3.x = (float)p1[4]; f3.y = (float)p1[5]; f3.z = (float)p1[6]; f3.w = (float)p1[7];
                    *(float4*)(wp + jj*16)      = f0;
                    *(float4*)(wp + jj*16 + 4)  = f1;
                    *(float4*)(wp + jj*16 + 8)  = f2;
                    *(float4*)(wp + jj*16 + 12) = f3;
                }
            }
            ++ai;
        } else {
            // masked k tile: w columns are exact zeros, no compute
            int row = t >> 1, ch = (t & 1) << 5;
            float4 z4 = {0.f, 0.f, 0.f, 0.f};
            float* wp = w + wqbase + ((size_t)row << 10) + kc0 + ch;
            #pragma unroll
            for (int jj = 0; jj < 8; ++jj)
                *(float4*)(wp + (jj << 2)) = z4;
            if (nextok) {
                kr0 = *(const bf16x8*)(Kp + ((size_t)(fb + nk0 + sr) << 9) + (h << 6) + sc);
                kr1 = *(const bf16x8*)(Kp + ((size_t)(fb + nk0 + 32 + sr) << 9) + (h << 6) + sc);
                vr0 = *(const bf16x8*)(Vt + ((size_t)bh << 16) + ((size_t)sr << 10) + nk0 + sc);
                vr1 = *(const bf16x8*)(Vt + ((size_t)bh << 16) + ((size_t)(32 + sr) << 10) + nk0 + sc);
            }
        }
        curok = nextok;
    }
    // epilogue: attn = O + Q, plus fused stats2 partial sums
    float s1 = 0.f, s2 = 0.f;
    #pragma unroll
    for (int g = 0; g < 2; ++g)
        #pragma unroll
        for (int nt2 = 0; nt2 < 4; ++nt2) {
            int d = nt2 * 16 + l16;
            #pragma unroll
            for (int r = 0; r < 4; ++r) {
                int row = q0 + wave*32 + g*16 + quad*4 + r;
                size_t off = ((size_t)(fb + row) << 9) + (h << 6) + d;
                float v = accO[g][nt2][r] + Q[off];
                attn[off] = v;
                s1 += v; s2 += v * v;
            }
        }
    #pragma unroll
    for (int o = 32; o > 0; o >>= 1) {
        s1 += __shfl_xor(s1, o);
        s2 += __shfl_xor(s2, o);
    }
    if (lane == 0) { red[wave * 2] = s1; red[wave * 2 + 1] = s2; }
    __syncthreads();
    if (t == 0) {
        atomicAdd(&stats[I_SUM2 + b], red[0] + red[2] + red[4] + red[6]);
        atomicAdd(&stats[I_SS2 + b], red[1] + red[3] + red[5] + red[7]);
    }
}

// ---------------- out = attn + relu(norm2(attn) @ Wo + bo) ------------------
__global__ __launch_bounds__(256) void final_gemm(
    const float* __restrict__ attn, const float* __restrict__ stats,
    const float* __restrict__ fmask, const __bf16* __restrict__ Wot,
    const float* __restrict__ bo, float* __restrict__ out)
{
    int t = threadIdx.x;
    int m0 = blockIdx.y << 6, n0 = blockIdx.x << 6;
    const int* ip = (const int*)stats;
    if (!ip[I_TMASK + (m0 >> 6)]) {
        int m = t >> 2, c = (t & 3) << 4;
        size_t base = ((size_t)(m0 + m) << 9) + n0 + c;
        #pragma unroll
        for (int i = 0; i < 4; ++i) {
            float4 a = *(const float4*)(attn + base + i * 4);
            float4 bb = *(const float4*)(bo + n0 + c + i * 4);
            float4 o;
            o.x = a.x + fmaxf(bb.x, 0.f); o.y = a.y + fmaxf(bb.y, 0.f);
            o.z = a.z + fmaxf(bb.z, 0.f); o.w = a.w + fmaxf(bb.w, 0.f);
            *(float4*)(out + base + i * 4) = o;
        }
        return;
    }
    __shared__ __align__(16) __bf16 smem[64 * LDSTRIDE * 2];
    __bf16* As = smem;
    __bf16* Bs = smem + 64 * LDSTRIDE;
    int srow = t >> 2, skp = (t & 3) << 3;
    int arow = m0 + srow, ab = arow >> 10;
    float fi   = fmask[arow] * stats[I_INV2 + ab];
    float mean = stats[I_MEAN2 + ab];
    int wave = t >> 6, lane = t & 63, quad = lane >> 4, l16 = lane & 15;
    int aoff  = (wave * 16 + l16) * LDSTRIDE + quad * 8;
    int boff0 = l16 * LDSTRIDE + quad * 8;
    f32x4 acc[4] = {};
    const float*  Arow = attn + ((size_t)arow << 9);
    const __bf16* Brow = Wot + ((size_t)(n0 + srow) << 9);
    float4 a0 = *(const float4*)(Arow + skp);
    float4 a1 = *(const float4*)(Arow + skp + 4);
    bf16x8 bw = *(const bf16x8*)(Brow + skp);
    for (int k0 = 0; k0 < 512; k0 += 32) {
        bf16x8 av;
        av[0] = (__bf16)((a0.x - mean) * fi); av[1] = (__bf16)((a0.y - mean) * fi);
        av[2] = (__bf16)((a0.z - mean) * fi); av[3] = (__bf16)((a0.w - mean) * fi);
        av[4] = (__bf16)((a1.x - mean) * fi); av[5] = (__bf16)((a1.y - mean) * fi);
        av[6] = (__bf16)((a1.z - mean) * fi); av[7] = (__bf16)((a1.w - mean) * fi);
        *(bf16x8*)&As[srow * LDSTRIDE + skp] = av;
        *(bf16x8*)&Bs[srow * LDSTRIDE + skp] = bw;
        __syncthreads();
        if (k0 < 480) {
            a0 = *(const float4*)(Arow + k0 + 32 + skp);
            a1 = *(const float4*)(Arow + k0 + 36 + skp);
            bw = *(const bf16x8*)(Brow + k0 + 32 + skp);
        }
        bf16x8 af = *(const bf16x8*)&As[aoff];
        #pragma unroll
        for (int nt = 0; nt < 4; ++nt)
            acc[nt] = MFMA16(af, *(const bf16x8*)&Bs[boff0 + nt * (16 * LDSTRIDE)], acc[nt]);
        __syncthreads();
    }
    #pragma unroll
    for (int nt = 0; nt < 4; ++nt) {
        int n = n0 + nt * 16 + l16;
        float bn = bo[n];
        #pragma unroll
        for (int reg = 0; reg < 4; ++reg) {
            int m = m0 + wave * 16 + quad * 4 + reg;
            size_t off = ((size_t)m << 9) + n;
            out[off] = attn[off] + fmaxf(acc[nt][reg] + bn, 0.f);
        }
    }
}

extern "C" void kernel_launch(void* const* d_in, const int* in_sizes, int n_in,
                              void* d_out, int out_size, void* d_ws, size_t ws_size,
                              hipStream_t stream) {
    const float* Q  = (const float*)d_in[0];
    const float* Wq = (const float*)d_in[1];
    const float* bq = (const float*)d_in[2];
    const float* Wk = (const float*)d_in[3];
    const float* bk = (const float*)d_in[4];
    const float* Wv = (const float*)d_in[5];
    const float* bv = (const float*)d_in[6];
    const float* Wo = (const float*)d_in[7];
    const float* bo = (const float*)d_in[8];
    float* out = (float*)d_out;                       // (B,S,D) = 4194304 floats
    float* w   = out + (size_t)BB * SS * DD;          // (B,H,S,S) = 67108864 floats

    char* ws = (char*)d_ws;
    float* stats  = (float*)ws;                       // 4 KB reserved (floats + tile masks)
    float* fmask  = (float*)(ws + 4096);              // 32 KB
    __bf16* Wt = (__bf16*)(ws + 4096 + 32768);        // 4 x 512x512 bf16 = 2 MB
    __bf16* Qp = Wt + ((size_t)4 << 18);              // each 8 MB
    __bf16* Kp = Qp + ((size_t)NROWS * DD);
    __bf16* Vt = Kp + ((size_t)NROWS * DD);           // [bh][64][1024] bf16 = 8 MB
    float* attn = (float*)(Vt + ((size_t)NROWS * DD)); // 16 MB fp32

    (void)hipMemsetAsync(stats, 0, 4096, stream);
    stats1_k<<<NROWS, 128, 0, stream>>>(Q, fmask, stats);
    finalize_k<<<1, 128, 0, stream>>>(stats, fmask, I_SUM1, I_SS1, I_CNT, I_MEAN1, I_INV1, 1);
    tw_k<<<dim3(8, 8, 4), 256, 0, stream>>>(Wq, Wk, Wv, Wo, Wt);
    projqkv_k<<<dim3(8, 128), 256, 0, stream>>>(Q, stats, fmask, Wt,
                                                bq, bk, bv, Qp, Kp, Vt);
    attn_k<<<dim3(8, 64), 256, 0, stream>>>(Qp, Kp, Vt, fmask, Q, stats, w, attn);
    finalize_k<<<1, 128, 0, stream>>>(stats, fmask, I_SUM2, I_SS2, I_CNT, I_MEAN2, I_INV2, 0);
    final_gemm<<<dim3(8, 128), 256, 0, stream>>>(attn, stats, fmask,
                                                 Wt + ((size_t)3 << 18), bo, out);
}

// Round 6
// 590.070 us; speedup vs baseline: 1.0586x; 1.0586x over previous
//
#include <hip/hip_runtime.h>
#include <math.h>

#define BB 8
#define SS 1024
#define DD 512
#define HH 8
#define NROWS (BB*SS)          // 8192
#define EPSV 1e-5f
#define SCALE_V 0.125f          // 1/sqrt(64)

// stats[] layout (floats)
#define I_SUM1 0
#define I_SS1  8
#define I_CNT  16
#define I_MEAN1 24
#define I_INV1 32
#define I_SUM2 40
#define I_SS2  48
#define I_MEAN2 56
#define I_INV2 64
// int region (indices into (int*)stats)
#define I_TMASK 96              // 128 per-64-row-tile valid flags
#define I_KBITS 224             // 8 per-batch 16-bit tile masks

typedef __bf16 bf16x8 __attribute__((ext_vector_type(8)));
typedef __bf16 bf16x4 __attribute__((ext_vector_type(4)));
typedef float f32x4 __attribute__((ext_vector_type(4)));

#define MFMA16(a,b,c) __builtin_amdgcn_mfma_f32_16x16x32_bf16(a,b,c,0,0,0)

// GEMM LDS tiles: 64 rows x 32 k bf16, padded stride 40 (2-way bank alias = free)
#define LDSTRIDE 40
#define GBUF (64 * LDSTRIDE)
// attention tiles: 64 rows x 64 k bf16, padded stride 72
#define ASTR 72

// ---------------- stats pass 1: fmask + masked sum/sumsq per batch ----------
__global__ __launch_bounds__(128) void stats1_k(const float* __restrict__ Q,
                                                float* __restrict__ fmask,
                                                float* __restrict__ stats) {
    int row = blockIdx.x;
    int b = row >> 10;
    int t = threadIdx.x;
    float4 v = *(const float4*)(Q + ((size_t)row << 9) + (t << 2));
    float s  = v.x + v.y + v.z + v.w;
    float ss = v.x*v.x + v.y*v.y + v.z*v.z + v.w*v.w;
    int nz = (v.x != 0.f) || (v.y != 0.f) || (v.z != 0.f) || (v.w != 0.f);
    __shared__ float rs[128], rss[128];
    __shared__ int rnz[128];
    rs[t] = s; rss[t] = ss; rnz[t] = nz;
    __syncthreads();
    for (int off = 64; off > 0; off >>= 1) {
        if (t < off) { rs[t] += rs[t+off]; rss[t] += rss[t+off]; rnz[t] |= rnz[t+off]; }
        __syncthreads();
    }
    if (t == 0) {
        float f = rnz[0] ? 1.f : 0.f;
        fmask[row] = f;
        if (f != 0.f) {
            atomicAdd(&stats[I_SUM1 + b], rs[0]);
            atomicAdd(&stats[I_SS1 + b], rss[0]);
            atomicAdd(&stats[I_CNT + b], 1.f);
        }
    }
}

// ---------------- finalize: mean/inv (+ tile masks on pass 1) ---------------
__global__ __launch_bounds__(128) void finalize_k(float* __restrict__ stats,
                                                  const float* __restrict__ fmask,
                                                  int osum, int oss, int ocnt,
                                                  int omean, int oinv, int dotile) {
    int t = threadIdx.x;
    if (t < BB) {
        float cntD = stats[ocnt + t] * 512.f;
        float mean = stats[osum + t] / cntD;
        float var  = stats[oss + t] / cntD - mean * mean;
        stats[omean + t] = mean;
        stats[oinv + t]  = rsqrtf(var + EPSV);
    }
    if (dotile) {
        int* ip = (int*)stats;
        const float* fr = fmask + (t << 6);
        int any = 0;
        for (int i = 0; i < 64; i += 4) {
            float4 v = *(const float4*)(fr + i);
            any |= (v.x != 0.f) | (v.y != 0.f) | (v.z != 0.f) | (v.w != 0.f);
        }
        ip[I_TMASK + t] = any;
        __syncthreads();
        if (t < BB) {
            int bits = 0;
            #pragma unroll
            for (int i = 0; i < 16; ++i)
                bits |= (ip[I_TMASK + (t << 4) + i] ? 1 : 0) << i;
            ip[I_KBITS + t] = bits;
        }
    }
}

// ---------------- transpose+cast weights: W[k][n] fp32 -> Wt[n][k] bf16 -----
__global__ __launch_bounds__(256) void tw_k(const float* __restrict__ Wq,
                                            const float* __restrict__ Wk,
                                            const float* __restrict__ Wv,
                                            const float* __restrict__ Wo,
                                            __bf16* __restrict__ Wt) {
    int z = blockIdx.z;
    const float* W = (z == 0) ? Wq : (z == 1) ? Wk : (z == 2) ? Wv : Wo;
    __bf16* dst = Wt + ((size_t)z << 18);
    __shared__ float tile[64][65];
    int t = threadIdx.x;
    int k0 = blockIdx.y << 6, n0 = blockIdx.x << 6;
    int r = t >> 4, c = (t & 15) << 2;
    #pragma unroll
    for (int i = 0; i < 4; ++i) {
        float4 v = *(const float4*)(W + (size_t)(k0 + r + i*16) * 512 + n0 + c);
        tile[r + i*16][c+0] = v.x; tile[r + i*16][c+1] = v.y;
        tile[r + i*16][c+2] = v.z; tile[r + i*16][c+3] = v.w;
    }
    __syncthreads();
    #pragma unroll
    for (int i = 0; i < 4; ++i) {
        int n = r + i*16;
        bf16x4 o;
        o[0] = (__bf16)tile[c+0][n]; o[1] = (__bf16)tile[c+1][n];
        o[2] = (__bf16)tile[c+2][n]; o[3] = (__bf16)tile[c+3][n];
        *(bf16x4*)(dst + (size_t)(n0 + n) * 512 + k0 + c) = o;
    }
}

// ---------------- fused set_norm + QKV projection (dbuf, 1 barrier/step) ----
__global__ __launch_bounds__(256) void projqkv_k(
    const float* __restrict__ Q, const float* __restrict__ stats,
    const float* __restrict__ fmask, const __bf16* __restrict__ Wt,
    const float* __restrict__ bq, const float* __restrict__ bk,
    const float* __restrict__ bv,
    __bf16* __restrict__ Qp, __bf16* __restrict__ Kp, __bf16* __restrict__ Vt)
{
    __shared__ __align__(16) __bf16 smem[GBUF * 8];   // 2 x (As + 3x Bs) = 40 KB
    int t = threadIdx.x;
    int m0 = blockIdx.y << 6, n0 = blockIdx.x << 6;
    int b = m0 >> 10, s0 = m0 & 1023, h = n0 >> 6;
    int bh = (b << 3) + h;
    const int* ip = (const int*)stats;
    if (!ip[I_TMASK + (m0 >> 6)]) {
        int m = t >> 2, ch = (t & 3) << 4;
        bf16x8 z = {};
        *(bf16x8*)(Qp + ((size_t)(m0 + m) << 9) + n0 + ch)     = z;
        *(bf16x8*)(Qp + ((size_t)(m0 + m) << 9) + n0 + ch + 8) = z;
        *(bf16x8*)(Kp + ((size_t)(m0 + m) << 9) + n0 + ch)     = z;
        *(bf16x8*)(Kp + ((size_t)(m0 + m) << 9) + n0 + ch + 8) = z;
        *(bf16x8*)(Vt + ((size_t)bh << 16) + ((size_t)m << 10) + s0 + ch)     = z;
        *(bf16x8*)(Vt + ((size_t)bh << 16) + ((size_t)m << 10) + s0 + ch + 8) = z;
        return;
    }
    int srow = t >> 2, skp = (t & 3) << 3;
    int arow = m0 + srow;
    float fi   = fmask[arow] * stats[I_INV1 + b];
    float mean = stats[I_MEAN1 + b];
    int wave = t >> 6, lane = t & 63, quad = lane >> 4, l16 = lane & 15;
    int aoff  = (wave * 16 + l16) * LDSTRIDE + quad * 8;
    int boff0 = l16 * LDSTRIDE + quad * 8;
    f32x4 acc[3][4] = {};
    const float*  Arow = Q + ((size_t)arow << 9);
    const __bf16* Brow = Wt + ((size_t)(n0 + srow) << 9);
    // prefetch k0=0
    float4 a0 = *(const float4*)(Arow + skp);
    float4 a1 = *(const float4*)(Arow + skp + 4);
    bf16x8 w0 = *(const bf16x8*)(Brow + skp);
    bf16x8 w1 = *(const bf16x8*)(Brow + (1 << 18) + skp);
    bf16x8 w2 = *(const bf16x8*)(Brow + (2 << 18) + skp);
    for (int k0 = 0; k0 < 512; k0 += 32) {
        __bf16* bb = smem + (((k0 >> 5) & 1) ? GBUF * 4 : 0);
        bf16x8 av;
        av[0] = (__bf16)((a0.x - mean) * fi); av[1] = (__bf16)((a0.y - mean) * fi);
        av[2] = (__bf16)((a0.z - mean) * fi); av[3] = (__bf16)((a0.w - mean) * fi);
        av[4] = (__bf16)((a1.x - mean) * fi); av[5] = (__bf16)((a1.y - mean) * fi);
        av[6] = (__bf16)((a1.z - mean) * fi); av[7] = (__bf16)((a1.w - mean) * fi);
        *(bf16x8*)&bb[srow * LDSTRIDE + skp] = av;
        *(bf16x8*)&bb[GBUF*1 + srow * LDSTRIDE + skp] = w0;
        *(bf16x8*)&bb[GBUF*2 + srow * LDSTRIDE + skp] = w1;
        *(bf16x8*)&bb[GBUF*3 + srow * LDSTRIDE + skp] = w2;
        __syncthreads();
        if (k0 < 480) {   // prefetch next K-step; completes under MFMA
            a0 = *(const float4*)(Arow + k0 + 32 + skp);
            a1 = *(const float4*)(Arow + k0 + 36 + skp);
            w0 = *(const bf16x8*)(Brow + k0 + 32 + skp);
            w1 = *(const bf16x8*)(Brow + (1 << 18) + k0 + 32 + skp);
            w2 = *(const bf16x8*)(Brow + (2 << 18) + k0 + 32 + skp);
        }
        bf16x8 af = *(const bf16x8*)&bb[aoff];
        #pragma unroll
        for (int nt = 0; nt < 4; ++nt) {
            int bo = boff0 + nt * (16 * LDSTRIDE);
            acc[0][nt] = MFMA16(af, *(const bf16x8*)&bb[GBUF*1 + bo], acc[0][nt]);
            acc[1][nt] = MFMA16(af, *(const bf16x8*)&bb[GBUF*2 + bo], acc[1][nt]);
            acc[2][nt] = MFMA16(af, *(const bf16x8*)&bb[GBUF*3 + bo], acc[2][nt]);
        }
        // no trailing barrier: next iter writes the other buffer
    }
    float fmr[4];
    #pragma unroll
    for (int reg = 0; reg < 4; ++reg) fmr[reg] = fmask[m0 + wave*16 + quad*4 + reg];
    __bf16* Cs = smem;    // buffer0 region; last loop reads were buffer1
    #pragma unroll
    for (int z = 0; z < 2; ++z) {
        const float* bias = z ? bk : bq;
        __bf16* C = z ? Kp : Qp;
        #pragma unroll
        for (int nt = 0; nt < 4; ++nt) {
            float bn = bias[n0 + nt * 16 + l16];
            #pragma unroll
            for (int reg = 0; reg < 4; ++reg) {
                int m = wave * 16 + quad * 4 + reg;
                Cs[m * 70 + nt * 16 + l16] = (__bf16)((acc[z][nt][reg] + bn) * fmr[reg]);
            }
        }
        __syncthreads();
        int m = t >> 2, ch = (t & 3) << 4;
        bf16x8 o0 = *(const bf16x8*)&Cs[m * 70 + ch];
        bf16x8 o1 = *(const bf16x8*)&Cs[m * 70 + ch + 8];
        *(bf16x8*)(C + ((size_t)(m0 + m) << 9) + n0 + ch)     = o0;
        *(bf16x8*)(C + ((size_t)(m0 + m) << 9) + n0 + ch + 8) = o1;
        __syncthreads();
    }
    // z=2: store transposed into Cs ([d][s]) then coalesced Vt write
    #pragma unroll
    for (int nt = 0; nt < 4; ++nt) {
        int d = nt * 16 + l16;
        float bn = bv[n0 + d];
        #pragma unroll
        for (int reg = 0; reg < 4; ++reg) {
            int sl = wave * 16 + quad * 4 + reg;
            Cs[d * 70 + sl] = (__bf16)((acc[2][nt][reg] + bn) * fmr[reg]);
        }
    }
    __syncthreads();
    {
        int d = t >> 2, seg = (t & 3) << 4;
        bf16x8 o0 = *(const bf16x8*)&Cs[d * 70 + seg];
        bf16x8 o1 = *(const bf16x8*)&Cs[d * 70 + seg + 8];
        *(bf16x8*)(Vt + ((size_t)bh << 16) + ((size_t)d << 10) + s0 + seg)     = o0;
        *(bf16x8*)(Vt + ((size_t)bh << 16) + ((size_t)d << 10) + s0 + seg + 8) = o1;
    }
}

// ---------------- fused attention: rowsum (phase A) + attn (phase B) --------
// (round-3 verified form, unchanged)
__global__ __launch_bounds__(256) void attn_k(
    const __bf16* __restrict__ Qp, const __bf16* __restrict__ Kp,
    const __bf16* __restrict__ Vt,
    const float* __restrict__ fmask, const float* __restrict__ Q,
    float* __restrict__ stats, float* __restrict__ w, float* __restrict__ attn)
{
    int bh = blockIdx.y, b = bh >> 3, h = bh & 7;
    int q0 = blockIdx.x << 6;
    int t = threadIdx.x;
    const int* ip = (const int*)stats;
    int kb = ip[I_KBITS + b];
    int fb = b << 10;
    size_t wqbase = ((size_t)bh << 20) + ((size_t)q0 << 10);
    if (!((kb >> (q0 >> 6)) & 1)) {
        // fully-masked q tile: w rows = 0, attn = Q; stats contribution 0
        int q = t >> 2, ch = (t & 3) << 4;
        float4 z4 = {0.f, 0.f, 0.f, 0.f};
        float* wp0 = w + wqbase + ((size_t)q << 10) + ch;
        #pragma unroll
        for (int kc0 = 0; kc0 < 1024; kc0 += 64) {
            *(float4*)(wp0 + kc0)      = z4;
            *(float4*)(wp0 + kc0 + 4)  = z4;
            *(float4*)(wp0 + kc0 + 8)  = z4;
            *(float4*)(wp0 + kc0 + 12) = z4;
        }
        size_t base = ((size_t)(fb + q0 + q) << 9) + (h << 6) + ch;
        #pragma unroll
        for (int i = 0; i < 4; ++i)
            *(float4*)(attn + base + i*4) = *(const float4*)(Q + base + i*4);
        return;
    }
    __shared__ __align__(16) __bf16 Ks[64 * ASTR];
    __shared__ __align__(16) __bf16 Vs[64 * ASTR];
    __shared__ __align__(16) __bf16 Ws[64 * ASTR];
    __shared__ float red[8];
    int wave = t >> 6, lane = t & 63, quad = lane >> 4, l16 = lane & 15;
    int sr = t >> 3, sc = (t & 7) << 3;
    // Q fragments: one-time direct gather
    const __bf16* Qr = Qp + ((size_t)(fb + q0 + wave*16 + l16) << 9) + (h << 6) + (quad << 3);
    bf16x8 qa0 = *(const bf16x8*)(Qr);
    bf16x8 qa1 = *(const bf16x8*)(Qr + 32);
    int aoff = (wave * 16 + l16) * ASTR + (quad << 3);

    // ---- phase A: row sums ----
    float rsum[4] = {0.f, 0.f, 0.f, 0.f};
    bf16x8 kr0, kr1;
    bool curok = kb & 1;
    if (curok) {
        kr0 = *(const bf16x8*)(Kp + ((size_t)(fb + sr) << 9) + (h << 6) + sc);
        kr1 = *(const bf16x8*)(Kp + ((size_t)(fb + 32 + sr) << 9) + (h << 6) + sc);
    }
    for (int kc = 0; kc < 16; ++kc) {
        bool nextok = (kc < 15) && ((kb >> (kc + 1)) & 1);
        int nbase = fb + ((kc + 1) << 6);
        if (curok) {
            *(bf16x8*)&Ks[sr * ASTR + sc] = kr0;
            *(bf16x8*)&Ks[(32 + sr) * ASTR + sc] = kr1;
            __syncthreads();
            if (nextok) {
                kr0 = *(const bf16x8*)(Kp + ((size_t)(nbase + sr) << 9) + (h << 6) + sc);
                kr1 = *(const bf16x8*)(Kp + ((size_t)(nbase + 32 + sr) << 9) + (h << 6) + sc);
            }
            int kc0 = kc << 6;
            #pragma unroll
            for (int nt = 0; nt < 4; ++nt) {
                int boff = (nt * 16 + l16) * ASTR + (quad << 3);
                f32x4 s = {};
                s = MFMA16(qa0, *(const bf16x8*)&Ks[boff], s);
                s = MFMA16(qa1, *(const bf16x8*)&Ks[boff + 32], s);
                float fk = fmask[fb + kc0 + nt * 16 + l16];
                #pragma unroll
                for (int r = 0; r < 4; ++r)
                    rsum[r] += (fk != 0.f) ? __expf(s[r] * SCALE_V) : 0.f;
            }
            __syncthreads();
        } else if (nextok) {
            kr0 = *(const bf16x8*)(Kp + ((size_t)(nbase + sr) << 9) + (h << 6) + sc);
            kr1 = *(const bf16x8*)(Kp + ((size_t)(nbase + 32 + sr) << 9) + (h << 6) + sc);
        }
        curok = nextok;
    }
    float inv[4];
    #pragma unroll
    for (int r = 0; r < 4; ++r) {
        float v = rsum[r];
        v += __shfl_xor(v, 1); v += __shfl_xor(v, 2);
        v += __shfl_xor(v, 4); v += __shfl_xor(v, 8);
        float fq = fmask[fb + q0 + wave * 16 + quad * 4 + r];
        inv[r] = (fq != 0.f && v > 0.f) ? 1.f / v : 0.f;
    }

    // ---- phase B: attention ----
    f32x4 accO[4] = {};
    bf16x8 vr0, vr1;
    curok = kb & 1;
    if (curok) {
        kr0 = *(const bf16x8*)(Kp + ((size_t)(fb + sr) << 9) + (h << 6) + sc);
        kr1 = *(const bf16x8*)(Kp + ((size_t)(fb + 32 + sr) << 9) + (h << 6) + sc);
        vr0 = *(const bf16x8*)(Vt + ((size_t)bh << 16) + ((size_t)sr << 10) + sc);
        vr1 = *(const bf16x8*)(Vt + ((size_t)bh << 16) + ((size_t)(32 + sr) << 10) + sc);
    }
    for (int kc = 0; kc < 16; ++kc) {
        int kc0 = kc << 6;
        bool nextok = (kc < 15) && ((kb >> (kc + 1)) & 1);
        int nk0 = kc0 + 64;
        if (curok) {
            *(bf16x8*)&Ks[sr * ASTR + sc] = kr0;
            *(bf16x8*)&Ks[(32 + sr) * ASTR + sc] = kr1;
            *(bf16x8*)&Vs[sr * ASTR + sc] = vr0;
            *(bf16x8*)&Vs[(32 + sr) * ASTR + sc] = vr1;
            __syncthreads();
            if (nextok) {   // prefetch next K/V tile under QK^T+PV compute
                kr0 = *(const bf16x8*)(Kp + ((size_t)(fb + nk0 + sr) << 9) + (h << 6) + sc);
                kr1 = *(const bf16x8*)(Kp + ((size_t)(fb + nk0 + 32 + sr) << 9) + (h << 6) + sc);
                vr0 = *(const bf16x8*)(Vt + ((size_t)bh << 16) + ((size_t)sr << 10) + nk0 + sc);
                vr1 = *(const bf16x8*)(Vt + ((size_t)bh << 16) + ((size_t)(32 + sr) << 10) + nk0 + sc);
            }
            #pragma unroll
            for (int nt = 0; nt < 4; ++nt) {
                int boff = (nt * 16 + l16) * ASTR + (quad << 3);
                f32x4 s = {};
                s = MFMA16(qa0, *(const bf16x8*)&Ks[boff], s);
                s = MFMA16(qa1, *(const bf16x8*)&Ks[boff + 32], s);
                float fk = fmask[fb + kc0 + nt * 16 + l16];
                #pragma unroll
                for (int r = 0; r < 4; ++r) {
                    float p = (fk != 0.f) ? __expf(s[r] * SCALE_V) * inv[r] : 0.f;
                    Ws[(wave * 16 + quad * 4 + r) * ASTR + nt * 16 + l16] = (__bf16)p;
                }
            }
            __syncthreads();
            bf16x8 pa0 = *(const bf16x8*)&Ws[aoff];
            bf16x8 pa1 = *(const bf16x8*)&Ws[aoff + 32];
            #pragma unroll
            for (int nt = 0; nt < 4; ++nt) {
                int boff = (nt * 16 + l16) * ASTR + (quad << 3);
                accO[nt] = MFMA16(pa0, *(const bf16x8*)&Vs[boff], accO[nt]);
                accO[nt] = MFMA16(pa1, *(const bf16x8*)&Vs[boff + 32], accO[nt]);
            }
            {
                int q = t >> 2, ch = (t & 3) << 4;
                bf16x8 w0 = *(const bf16x8*)&Ws[q * ASTR + ch];
                bf16x8 w1 = *(const bf16x8*)&Ws[q * ASTR + ch + 8];
                float4 f0, f1, f2, f3;
                f0.x = (float)w0[0]; f0.y = (float)w0[1]; f0.z = (float)w0[2]; f0.w = (float)w0[3];
                f1.x = (float)w0[4]; f1.y = (float)w0[5]; f1.z = (float)w0[6]; f1.w = (float)w0[7];
                f2.x = (float)w1[0]; f2.y = (float)w1[1]; f2.z = (float)w1[2]; f2.w = (float)w1[3];
                f3.x = (float)w1[4]; f3.y = (float)w1[5]; f3.z = (float)w1[6]; f3.w = (float)w1[7];
                float* wp = w + wqbase + ((size_t)q << 10) + kc0 + ch;
                *(float4*)(wp)      = f0;
                *(float4*)(wp + 4)  = f1;
                *(float4*)(wp + 8)  = f2;
                *(float4*)(wp + 12) = f3;
            }
            __syncthreads();
        } else {
            // masked k tile: w columns are exact zeros, no compute
            int q = t >> 2, ch = (t & 3) << 4;
            float4 z4 = {0.f, 0.f, 0.f, 0.f};
            float* wp = w + wqbase + ((size_t)q << 10) + kc0 + ch;
            *(float4*)(wp)      = z4;
            *(float4*)(wp + 4)  = z4;
            *(float4*)(wp + 8)  = z4;
            *(float4*)(wp + 12) = z4;
            if (nextok) {
                kr0 = *(const bf16x8*)(Kp + ((size_t)(fb + nk0 + sr) << 9) + (h << 6) + sc);
                kr1 = *(const bf16x8*)(Kp + ((size_t)(fb + nk0 + 32 + sr) << 9) + (h << 6) + sc);
                vr0 = *(const bf16x8*)(Vt + ((size_t)bh << 16) + ((size_t)sr << 10) + nk0 + sc);
                vr1 = *(const bf16x8*)(Vt + ((size_t)bh << 16) + ((size_t)(32 + sr) << 10) + nk0 + sc);
            }
        }
        curok = nextok;
    }
    // epilogue: attn = O + Q, plus fused stats2 partial sums
    float s1 = 0.f, s2 = 0.f;
    #pragma unroll
    for (int nt = 0; nt < 4; ++nt) {
        int d = nt * 16 + l16;
        #pragma unroll
        for (int r = 0; r < 4; ++r) {
            int q = q0 + wave * 16 + quad * 4 + r;
            size_t off = ((size_t)(fb + q) << 9) + (h << 6) + d;
            float v = accO[nt][r] + Q[off];
            attn[off] = v;
            s1 += v; s2 += v * v;
        }
    }
    #pragma unroll
    for (int o = 32; o > 0; o >>= 1) {
        s1 += __shfl_xor(s1, o);
        s2 += __shfl_xor(s2, o);
    }
    if (lane == 0) { red[wave * 2] = s1; red[wave * 2 + 1] = s2; }
    __syncthreads();
    if (t == 0) {
        atomicAdd(&stats[I_SUM2 + b], red[0] + red[2] + red[4] + red[6]);
        atomicAdd(&stats[I_SS2 + b], red[1] + red[3] + red[5] + red[7]);
    }
}

// ---------------- out = attn + relu(norm2(attn) @ Wo + bo) (dbuf) -----------
__global__ __launch_bounds__(256) void final_gemm(
    const float* __restrict__ attn, const float* __restrict__ stats,
    const float* __restrict__ fmask, const __bf16* __restrict__ Wot,
    const float* __restrict__ bo, float* __restrict__ out)
{
    int t = threadIdx.x;
    int m0 = blockIdx.y << 6, n0 = blockIdx.x << 6;
    const int* ip = (const int*)stats;
    if (!ip[I_TMASK + (m0 >> 6)]) {
        int m = t >> 2, c = (t & 3) << 4;
        size_t base = ((size_t)(m0 + m) << 9) + n0 + c;
        #pragma unroll
        for (int i = 0; i < 4; ++i) {
            float4 a = *(const float4*)(attn + base + i * 4);
            float4 bb = *(const float4*)(bo + n0 + c + i * 4);
            float4 o;
            o.x = a.x + fmaxf(bb.x, 0.f); o.y = a.y + fmaxf(bb.y, 0.f);
            o.z = a.z + fmaxf(bb.z, 0.f); o.w = a.w + fmaxf(bb.w, 0.f);
            *(float4*)(out + base + i * 4) = o;
        }
        return;
    }
    __shared__ __align__(16) __bf16 smem[GBUF * 4];   // 2 x (As + Bs) = 20 KB
    int srow = t >> 2, skp = (t & 3) << 3;
    int arow = m0 + srow, ab = arow >> 10;
    float fi   = fmask[arow] * stats[I_INV2 + ab];
    float mean = stats[I_MEAN2 + ab];
    int wave = t >> 6, lane = t & 63, quad = lane >> 4, l16 = lane & 15;
    int aoff  = (wave * 16 + l16) * LDSTRIDE + quad * 8;
    int boff0 = l16 * LDSTRIDE + quad * 8;
    f32x4 acc[4] = {};
    const float*  Arow = attn + ((size_t)arow << 9);
    const __bf16* Brow = Wot + ((size_t)(n0 + srow) << 9);
    float4 a0 = *(const float4*)(Arow + skp);
    float4 a1 = *(const float4*)(Arow + skp + 4);
    bf16x8 bw = *(const bf16x8*)(Brow + skp);
    for (int k0 = 0; k0 < 512; k0 += 32) {
        __bf16* bb = smem + (((k0 >> 5) & 1) ? GBUF * 2 : 0);
        bf16x8 av;
        av[0] = (__bf16)((a0.x - mean) * fi); av[1] = (__bf16)((a0.y - mean) * fi);
        av[2] = (__bf16)((a0.z - mean) * fi); av[3] = (__bf16)((a0.w - mean) * fi);
        av[4] = (__bf16)((a1.x - mean) * fi); av[5] = (__bf16)((a1.y - mean) * fi);
        av[6] = (__bf16)((a1.z - mean) * fi); av[7] = (__bf16)((a1.w - mean) * fi);
        *(bf16x8*)&bb[srow * LDSTRIDE + skp] = av;
        *(bf16x8*)&bb[GBUF + srow * LDSTRIDE + skp] = bw;
        __syncthreads();
        if (k0 < 480) {
            a0 = *(const float4*)(Arow + k0 + 32 + skp);
            a1 = *(const float4*)(Arow + k0 + 36 + skp);
            bw = *(const bf16x8*)(Brow + k0 + 32 + skp);
        }
        bf16x8 af = *(const bf16x8*)&bb[aoff];
        #pragma unroll
        for (int nt = 0; nt < 4; ++nt)
            acc[nt] = MFMA16(af, *(const bf16x8*)&bb[GBUF + boff0 + nt * (16 * LDSTRIDE)], acc[nt]);
        // no trailing barrier: next iter writes the other buffer
    }
    #pragma unroll
    for (int nt = 0; nt < 4; ++nt) {
        int n = n0 + nt * 16 + l16;
        float bn = bo[n];
        #pragma unroll
        for (int reg = 0; reg < 4; ++reg) {
            int m = m0 + wave * 16 + quad * 4 + reg;
            size_t off = ((size_t)m << 9) + n;
            out[off] = attn[off] + fmaxf(acc[nt][reg] + bn, 0.f);
        }
    }
}

extern "C" void kernel_launch(void* const* d_in, const int* in_sizes, int n_in,
                              void* d_out, int out_size, void* d_ws, size_t ws_size,
                              hipStream_t stream) {
    const float* Q  = (const float*)d_in[0];
    const float* Wq = (const float*)d_in[1];
    const float* bq = (const float*)d_in[2];
    const float* Wk = (const float*)d_in[3];
    const float* bk = (const float*)d_in[4];
    const float* Wv = (const float*)d_in[5];
    const float* bv = (const float*)d_in[6];
    const float* Wo = (const float*)d_in[7];
    const float* bo = (const float*)d_in[8];
    float* out = (float*)d_out;                       // (B,S,D) = 4194304 floats
    float* w   = out + (size_t)BB * SS * DD;          // (B,H,S,S) = 67108864 floats

    char* ws = (char*)d_ws;
    float* stats  = (float*)ws;                       // 4 KB reserved (floats + tile masks)
    float* fmask  = (float*)(ws + 4096);              // 32 KB
    __bf16* Wt = (__bf16*)(ws + 4096 + 32768);        // 4 x 512x512 bf16 = 2 MB
    __bf16* Qp = Wt + ((size_t)4 << 18);              // each 8 MB
    __bf16* Kp = Qp + ((size_t)NROWS * DD);
    __bf16* Vt = Kp + ((size_t)NROWS * DD);           // [bh][64][1024] bf16 = 8 MB
    float* attn = (float*)(Vt + ((size_t)NROWS * DD)); // 16 MB fp32

    (void)hipMemsetAsync(stats, 0, 4096, stream);
    stats1_k<<<NROWS, 128, 0, stream>>>(Q, fmask, stats);
    finalize_k<<<1, 128, 0, stream>>>(stats, fmask, I_SUM1, I_SS1, I_CNT, I_MEAN1, I_INV1, 1);
    tw_k<<<dim3(8, 8, 4), 256, 0, stream>>>(Wq, Wk, Wv, Wo, Wt);
    projqkv_k<<<dim3(8, 128), 256, 0, stream>>>(Q, stats, fmask, Wt,
                                                bq, bk, bv, Qp, Kp, Vt);
    attn_k<<<dim3(16, 64), 256, 0, stream>>>(Qp, Kp, Vt, fmask, Q, stats, w, attn);
    finalize_k<<<1, 128, 0, stream>>>(stats, fmask, I_SUM2, I_SS2, I_CNT, I_MEAN2, I_INV2, 0);
    final_gemm<<<dim3(8, 128), 256, 0, stream>>>(attn, stats, fmask,
                                                 Wt + ((size_t)3 << 18), bo, out);
}

// Round 7
// 580.539 us; speedup vs baseline: 1.0760x; 1.0164x over previous
//
#include <hip/hip_runtime.h>
#include <math.h>

#define BB 8
#define SS 1024
#define DD 512
#define HH 8
#define NROWS (BB*SS)          // 8192
#define EPSV 1e-5f
#define SCALE_V 0.125f          // 1/sqrt(64)

// stats[] layout (floats)
#define I_SUM1 0
#define I_SS1  8
#define I_CNT  16
#define I_SUM2 40
#define I_SS2  48
// int region (indices into (int*)stats)
#define I_TMASK 96              // 128 per-64-row-tile valid flags (atomicOr 0/1)

typedef __bf16 bf16x8 __attribute__((ext_vector_type(8)));
typedef __bf16 bf16x4 __attribute__((ext_vector_type(4)));
typedef float f32x4 __attribute__((ext_vector_type(4)));

#define MFMA16(a,b,c) __builtin_amdgcn_mfma_f32_16x16x32_bf16(a,b,c,0,0,0)

// GEMM LDS tiles: 64 rows x 32 k bf16, padded stride 40 (2-way bank alias = free)
#define LDSTRIDE 40
#define GBUF (64 * LDSTRIDE)
// attention tiles: 64 rows x 64 k bf16, padded stride 72
#define ASTR 72

// ---------------- pre pass: stats1 (blocks 0..8191) + weight transpose ------
// (blocks 8192..8447). Independent work fused into one launch.
__global__ __launch_bounds__(256) void pre_k(
    const float* __restrict__ Q,
    const float* __restrict__ Wq, const float* __restrict__ Wk,
    const float* __restrict__ Wv, const float* __restrict__ Wo,
    float* __restrict__ fmask, float* __restrict__ stats,
    __bf16* __restrict__ Wt)
{
    int bid = blockIdx.x;
    int t = threadIdx.x;
    if (bid < NROWS) {
        // ---- stats1: fmask + masked sum/sumsq per batch ----
        int row = bid;
        int b = row >> 10;
        float2 v = *(const float2*)(Q + ((size_t)row << 9) + (t << 1));
        float s  = v.x + v.y;
        float ss = v.x*v.x + v.y*v.y;
        int nz = (v.x != 0.f) || (v.y != 0.f);
        __shared__ float rs[256], rss[256];
        __shared__ int rnz[256];
        rs[t] = s; rss[t] = ss; rnz[t] = nz;
        __syncthreads();
        for (int off = 128; off > 0; off >>= 1) {
            if (t < off) { rs[t] += rs[t+off]; rss[t] += rss[t+off]; rnz[t] |= rnz[t+off]; }
            __syncthreads();
        }
        if (t == 0) {
            float f = rnz[0] ? 1.f : 0.f;
            fmask[row] = f;
            if (f != 0.f) {
                atomicAdd(&stats[I_SUM1 + b], rs[0]);
                atomicAdd(&stats[I_SS1 + b], rss[0]);
                atomicAdd(&stats[I_CNT + b], 1.f);
                atomicOr(&((int*)stats)[I_TMASK + (row >> 6)], 1);
            }
        }
        return;
    }
    // ---- weight transpose+cast: W[k][n] fp32 -> Wt[n][k] bf16 ----
    int q = bid - NROWS;
    int z = q >> 6, rem = q & 63;
    int k0 = (rem >> 3) << 6, n0 = (rem & 7) << 6;
    const float* W = (z == 0) ? Wq : (z == 1) ? Wk : (z == 2) ? Wv : Wo;
    __bf16* dst = Wt + ((size_t)z << 18);
    __shared__ float tile[64][65];
    int r = t >> 4, c = (t & 15) << 2;
    #pragma unroll
    for (int i = 0; i < 4; ++i) {
        float4 v = *(const float4*)(W + (size_t)(k0 + r + i*16) * 512 + n0 + c);
        tile[r + i*16][c+0] = v.x; tile[r + i*16][c+1] = v.y;
        tile[r + i*16][c+2] = v.z; tile[r + i*16][c+3] = v.w;
    }
    __syncthreads();
    #pragma unroll
    for (int i = 0; i < 4; ++i) {
        int n = r + i*16;
        bf16x4 o;
        o[0] = (__bf16)tile[c+0][n]; o[1] = (__bf16)tile[c+1][n];
        o[2] = (__bf16)tile[c+2][n]; o[3] = (__bf16)tile[c+3][n];
        *(bf16x4*)(dst + (size_t)(n0 + n) * 512 + k0 + c) = o;
    }
}

// ---------------- fused set_norm + QKV projection (dbuf, 1 barrier/step) ----
// mean/inv computed per-block from raw sums (identical arithmetic to the old
// finalize kernel: sum/cnt, rsqrt(var+eps)).
__global__ __launch_bounds__(256) void projqkv_k(
    const float* __restrict__ Q, const float* __restrict__ stats,
    const float* __restrict__ fmask, const __bf16* __restrict__ Wt,
    const float* __restrict__ bq, const float* __restrict__ bk,
    const float* __restrict__ bv,
    __bf16* __restrict__ Qp, __bf16* __restrict__ Kp, __bf16* __restrict__ Vt)
{
    __shared__ __align__(16) __bf16 smem[GBUF * 8];   // 2 x (As + 3x Bs) = 40 KB
    int t = threadIdx.x;
    int m0 = blockIdx.y << 6, n0 = blockIdx.x << 6;
    int b = m0 >> 10, s0 = m0 & 1023, h = n0 >> 6;
    int bh = (b << 3) + h;
    const int* ip = (const int*)stats;
    if (!ip[I_TMASK + (m0 >> 6)]) {
        int m = t >> 2, ch = (t & 3) << 4;
        bf16x8 z = {};
        *(bf16x8*)(Qp + ((size_t)(m0 + m) << 9) + n0 + ch)     = z;
        *(bf16x8*)(Qp + ((size_t)(m0 + m) << 9) + n0 + ch + 8) = z;
        *(bf16x8*)(Kp + ((size_t)(m0 + m) << 9) + n0 + ch)     = z;
        *(bf16x8*)(Kp + ((size_t)(m0 + m) << 9) + n0 + ch + 8) = z;
        *(bf16x8*)(Vt + ((size_t)bh << 16) + ((size_t)m << 10) + s0 + ch)     = z;
        *(bf16x8*)(Vt + ((size_t)bh << 16) + ((size_t)m << 10) + s0 + ch + 8) = z;
        return;
    }
    int srow = t >> 2, skp = (t & 3) << 3;
    int arow = m0 + srow;
    float cntD = stats[I_CNT + b] * 512.f;
    float mean = stats[I_SUM1 + b] / cntD;
    float var  = stats[I_SS1 + b] / cntD - mean * mean;
    float inv1 = rsqrtf(var + EPSV);
    float fi   = fmask[arow] * inv1;
    int wave = t >> 6, lane = t & 63, quad = lane >> 4, l16 = lane & 15;
    int aoff  = (wave * 16 + l16) * LDSTRIDE + quad * 8;
    int boff0 = l16 * LDSTRIDE + quad * 8;
    f32x4 acc[3][4] = {};
    const float*  Arow = Q + ((size_t)arow << 9);
    const __bf16* Brow = Wt + ((size_t)(n0 + srow) << 9);
    // prefetch k0=0
    float4 a0 = *(const float4*)(Arow + skp);
    float4 a1 = *(const float4*)(Arow + skp + 4);
    bf16x8 w0 = *(const bf16x8*)(Brow + skp);
    bf16x8 w1 = *(const bf16x8*)(Brow + (1 << 18) + skp);
    bf16x8 w2 = *(const bf16x8*)(Brow + (2 << 18) + skp);
    for (int k0 = 0; k0 < 512; k0 += 32) {
        __bf16* bb = smem + (((k0 >> 5) & 1) ? GBUF * 4 : 0);
        bf16x8 av;
        av[0] = (__bf16)((a0.x - mean) * fi); av[1] = (__bf16)((a0.y - mean) * fi);
        av[2] = (__bf16)((a0.z - mean) * fi); av[3] = (__bf16)((a0.w - mean) * fi);
        av[4] = (__bf16)((a1.x - mean) * fi); av[5] = (__bf16)((a1.y - mean) * fi);
        av[6] = (__bf16)((a1.z - mean) * fi); av[7] = (__bf16)((a1.w - mean) * fi);
        *(bf16x8*)&bb[srow * LDSTRIDE + skp] = av;
        *(bf16x8*)&bb[GBUF*1 + srow * LDSTRIDE + skp] = w0;
        *(bf16x8*)&bb[GBUF*2 + srow * LDSTRIDE + skp] = w1;
        *(bf16x8*)&bb[GBUF*3 + srow * LDSTRIDE + skp] = w2;
        __syncthreads();
        if (k0 < 480) {   // prefetch next K-step; completes under MFMA
            a0 = *(const float4*)(Arow + k0 + 32 + skp);
            a1 = *(const float4*)(Arow + k0 + 36 + skp);
            w0 = *(const bf16x8*)(Brow + k0 + 32 + skp);
            w1 = *(const bf16x8*)(Brow + (1 << 18) + k0 + 32 + skp);
            w2 = *(const bf16x8*)(Brow + (2 << 18) + k0 + 32 + skp);
        }
        bf16x8 af = *(const bf16x8*)&bb[aoff];
        #pragma unroll
        for (int nt = 0; nt < 4; ++nt) {
            int bo = boff0 + nt * (16 * LDSTRIDE);
            acc[0][nt] = MFMA16(af, *(const bf16x8*)&bb[GBUF*1 + bo], acc[0][nt]);
            acc[1][nt] = MFMA16(af, *(const bf16x8*)&bb[GBUF*2 + bo], acc[1][nt]);
            acc[2][nt] = MFMA16(af, *(const bf16x8*)&bb[GBUF*3 + bo], acc[2][nt]);
        }
        // no trailing barrier: next iter writes the other buffer
    }
    float fmr[4];
    #pragma unroll
    for (int reg = 0; reg < 4; ++reg) fmr[reg] = fmask[m0 + wave*16 + quad*4 + reg];
    __bf16* Cs = smem;    // buffer0 region; last loop reads were buffer1
    #pragma unroll
    for (int z = 0; z < 2; ++z) {
        const float* bias = z ? bk : bq;
        __bf16* C = z ? Kp : Qp;
        #pragma unroll
        for (int nt = 0; nt < 4; ++nt) {
            float bn = bias[n0 + nt * 16 + l16];
            #pragma unroll
            for (int reg = 0; reg < 4; ++reg) {
                int m = wave * 16 + quad * 4 + reg;
                Cs[m * 70 + nt * 16 + l16] = (__bf16)((acc[z][nt][reg] + bn) * fmr[reg]);
            }
        }
        __syncthreads();
        int m = t >> 2, ch = (t & 3) << 4;
        bf16x8 o0 = *(const bf16x8*)&Cs[m * 70 + ch];
        bf16x8 o1 = *(const bf16x8*)&Cs[m * 70 + ch + 8];
        *(bf16x8*)(C + ((size_t)(m0 + m) << 9) + n0 + ch)     = o0;
        *(bf16x8*)(C + ((size_t)(m0 + m) << 9) + n0 + ch + 8) = o1;
        __syncthreads();
    }
    // z=2: store transposed into Cs ([d][s]) then coalesced Vt write
    #pragma unroll
    for (int nt = 0; nt < 4; ++nt) {
        int d = nt * 16 + l16;
        float bn = bv[n0 + d];
        #pragma unroll
        for (int reg = 0; reg < 4; ++reg) {
            int sl = wave * 16 + quad * 4 + reg;
            Cs[d * 70 + sl] = (__bf16)((acc[2][nt][reg] + bn) * fmr[reg]);
        }
    }
    __syncthreads();
    {
        int d = t >> 2, seg = (t & 3) << 4;
        bf16x8 o0 = *(const bf16x8*)&Cs[d * 70 + seg];
        bf16x8 o1 = *(const bf16x8*)&Cs[d * 70 + seg + 8];
        *(bf16x8*)(Vt + ((size_t)bh << 16) + ((size_t)d << 10) + s0 + seg)     = o0;
        *(bf16x8*)(Vt + ((size_t)bh << 16) + ((size_t)d << 10) + s0 + seg + 8) = o1;
    }
}

// ---------------- fused attention: rowsum (phase A) + attn (phase B) --------
// kb assembled from the per-tile mask ints; stats2 atomics fused in epilogue.
__global__ __launch_bounds__(256) void attn_k(
    const __bf16* __restrict__ Qp, const __bf16* __restrict__ Kp,
    const __bf16* __restrict__ Vt,
    const float* __restrict__ fmask, const float* __restrict__ Q,
    float* __restrict__ stats, float* __restrict__ w, float* __restrict__ attn)
{
    int bh = blockIdx.y, b = bh >> 3, h = bh & 7;
    int q0 = blockIdx.x << 6;
    int t = threadIdx.x;
    const int* ip = (const int*)stats;
    const int* tm = ip + I_TMASK + (b << 4);
    int kb = 0;
    #pragma unroll
    for (int i = 0; i < 16; ++i) kb |= (tm[i] ? 1 : 0) << i;
    int fb = b << 10;
    size_t wqbase = ((size_t)bh << 20) + ((size_t)q0 << 10);
    if (!((kb >> (q0 >> 6)) & 1)) {
        // fully-masked q tile: w rows = 0, attn = Q; stats contribution 0
        int q = t >> 2, ch = (t & 3) << 4;
        float4 z4 = {0.f, 0.f, 0.f, 0.f};
        float* wp0 = w + wqbase + ((size_t)q << 10) + ch;
        #pragma unroll
        for (int kc0 = 0; kc0 < 1024; kc0 += 64) {
            *(float4*)(wp0 + kc0)      = z4;
            *(float4*)(wp0 + kc0 + 4)  = z4;
            *(float4*)(wp0 + kc0 + 8)  = z4;
            *(float4*)(wp0 + kc0 + 12) = z4;
        }
        size_t base = ((size_t)(fb + q0 + q) << 9) + (h << 6) + ch;
        #pragma unroll
        for (int i = 0; i < 4; ++i)
            *(float4*)(attn + base + i*4) = *(const float4*)(Q + base + i*4);
        return;
    }
    __shared__ __align__(16) __bf16 Ks[64 * ASTR];
    __shared__ __align__(16) __bf16 Vs[64 * ASTR];
    __shared__ __align__(16) __bf16 Ws[64 * ASTR];
    __shared__ float red[8];
    int wave = t >> 6, lane = t & 63, quad = lane >> 4, l16 = lane & 15;
    int sr = t >> 3, sc = (t & 7) << 3;
    // Q fragments: one-time direct gather
    const __bf16* Qr = Qp + ((size_t)(fb + q0 + wave*16 + l16) << 9) + (h << 6) + (quad << 3);
    bf16x8 qa0 = *(const bf16x8*)(Qr);
    bf16x8 qa1 = *(const bf16x8*)(Qr + 32);
    int aoff = (wave * 16 + l16) * ASTR + (quad << 3);

    // ---- phase A: row sums ----
    float rsum[4] = {0.f, 0.f, 0.f, 0.f};
    bf16x8 kr0, kr1;
    bool curok = kb & 1;
    if (curok) {
        kr0 = *(const bf16x8*)(Kp + ((size_t)(fb + sr) << 9) + (h << 6) + sc);
        kr1 = *(const bf16x8*)(Kp + ((size_t)(fb + 32 + sr) << 9) + (h << 6) + sc);
    }
    for (int kc = 0; kc < 16; ++kc) {
        bool nextok = (kc < 15) && ((kb >> (kc + 1)) & 1);
        int nbase = fb + ((kc + 1) << 6);
        if (curok) {
            *(bf16x8*)&Ks[sr * ASTR + sc] = kr0;
            *(bf16x8*)&Ks[(32 + sr) * ASTR + sc] = kr1;
            __syncthreads();
            if (nextok) {
                kr0 = *(const bf16x8*)(Kp + ((size_t)(nbase + sr) << 9) + (h << 6) + sc);
                kr1 = *(const bf16x8*)(Kp + ((size_t)(nbase + 32 + sr) << 9) + (h << 6) + sc);
            }
            int kc0 = kc << 6;
            #pragma unroll
            for (int nt = 0; nt < 4; ++nt) {
                int boff = (nt * 16 + l16) * ASTR + (quad << 3);
                f32x4 s = {};
                s = MFMA16(qa0, *(const bf16x8*)&Ks[boff], s);
                s = MFMA16(qa1, *(const bf16x8*)&Ks[boff + 32], s);
                float fk = fmask[fb + kc0 + nt * 16 + l16];
                #pragma unroll
                for (int r = 0; r < 4; ++r)
                    rsum[r] += (fk != 0.f) ? __expf(s[r] * SCALE_V) : 0.f;
            }
            __syncthreads();
        } else if (nextok) {
            kr0 = *(const bf16x8*)(Kp + ((size_t)(nbase + sr) << 9) + (h << 6) + sc);
            kr1 = *(const bf16x8*)(Kp + ((size_t)(nbase + 32 + sr) << 9) + (h << 6) + sc);
        }
        curok = nextok;
    }
    float inv[4];
    #pragma unroll
    for (int r = 0; r < 4; ++r) {
        float v = rsum[r];
        v += __shfl_xor(v, 1); v += __shfl_xor(v, 2);
        v += __shfl_xor(v, 4); v += __shfl_xor(v, 8);
        float fq = fmask[fb + q0 + wave * 16 + quad * 4 + r];
        inv[r] = (fq != 0.f && v > 0.f) ? 1.f / v : 0.f;
    }

    // ---- phase B: attention ----
    f32x4 accO[4] = {};
    bf16x8 vr0, vr1;
    curok = kb & 1;
    if (curok) {
        kr0 = *(const bf16x8*)(Kp + ((size_t)(fb + sr) << 9) + (h << 6) + sc);
        kr1 = *(const bf16x8*)(Kp + ((size_t)(fb + 32 + sr) << 9) + (h << 6) + sc);
        vr0 = *(const bf16x8*)(Vt + ((size_t)bh << 16) + ((size_t)sr << 10) + sc);
        vr1 = *(const bf16x8*)(Vt + ((size_t)bh << 16) + ((size_t)(32 + sr) << 10) + sc);
    }
    for (int kc = 0; kc < 16; ++kc) {
        int kc0 = kc << 6;
        bool nextok = (kc < 15) && ((kb >> (kc + 1)) & 1);
        int nk0 = kc0 + 64;
        if (curok) {
            *(bf16x8*)&Ks[sr * ASTR + sc] = kr0;
            *(bf16x8*)&Ks[(32 + sr) * ASTR + sc] = kr1;
            *(bf16x8*)&Vs[sr * ASTR + sc] = vr0;
            *(bf16x8*)&Vs[(32 + sr) * ASTR + sc] = vr1;
            __syncthreads();
            if (nextok) {   // prefetch next K/V tile under QK^T+PV compute
                kr0 = *(const bf16x8*)(Kp + ((size_t)(fb + nk0 + sr) << 9) + (h << 6) + sc);
                kr1 = *(const bf16x8*)(Kp + ((size_t)(fb + nk0 + 32 + sr) << 9) + (h << 6) + sc);
                vr0 = *(const bf16x8*)(Vt + ((size_t)bh << 16) + ((size_t)sr << 10) + nk0 + sc);
                vr1 = *(const bf16x8*)(Vt + ((size_t)bh << 16) + ((size_t)(32 + sr) << 10) + nk0 + sc);
            }
            #pragma unroll
            for (int nt = 0; nt < 4; ++nt) {
                int boff = (nt * 16 + l16) * ASTR + (quad << 3);
                f32x4 s = {};
                s = MFMA16(qa0, *(const bf16x8*)&Ks[boff], s);
                s = MFMA16(qa1, *(const bf16x8*)&Ks[boff + 32], s);
                float fk = fmask[fb + kc0 + nt * 16 + l16];
                #pragma unroll
                for (int r = 0; r < 4; ++r) {
                    float p = (fk != 0.f) ? __expf(s[r] * SCALE_V) * inv[r] : 0.f;
                    Ws[(wave * 16 + quad * 4 + r) * ASTR + nt * 16 + l16] = (__bf16)p;
                }
            }
            __syncthreads();
            bf16x8 pa0 = *(const bf16x8*)&Ws[aoff];
            bf16x8 pa1 = *(const bf16x8*)&Ws[aoff + 32];
            #pragma unroll
            for (int nt = 0; nt < 4; ++nt) {
                int boff = (nt * 16 + l16) * ASTR + (quad << 3);
                accO[nt] = MFMA16(pa0, *(const bf16x8*)&Vs[boff], accO[nt]);
                accO[nt] = MFMA16(pa1, *(const bf16x8*)&Vs[boff + 32], accO[nt]);
            }
            {
                int q = t >> 2, ch = (t & 3) << 4;
                bf16x8 w0 = *(const bf16x8*)&Ws[q * ASTR + ch];
                bf16x8 w1 = *(const bf16x8*)&Ws[q * ASTR + ch + 8];
                float4 f0, f1, f2, f3;
                f0.x = (float)w0[0]; f0.y = (float)w0[1]; f0.z = (float)w0[2]; f0.w = (float)w0[3];
                f1.x = (float)w0[4]; f1.y = (float)w0[5]; f1.z = (float)w0[6]; f1.w = (float)w0[7];
                f2.x = (float)w1[0]; f2.y = (float)w1[1]; f2.z = (float)w1[2]; f2.w = (float)w1[3];
                f3.x = (float)w1[4]; f3.y = (float)w1[5]; f3.z = (float)w1[6]; f3.w = (float)w1[7];
                float* wp = w + wqbase + ((size_t)q << 10) + kc0 + ch;
                *(float4*)(wp)      = f0;
                *(float4*)(wp + 4)  = f1;
                *(float4*)(wp + 8)  = f2;
                *(float4*)(wp + 12) = f3;
            }
            __syncthreads();
        } else {
            // masked k tile: w columns are exact zeros, no compute
            int q = t >> 2, ch = (t & 3) << 4;
            float4 z4 = {0.f, 0.f, 0.f, 0.f};
            float* wp = w + wqbase + ((size_t)q << 10) + kc0 + ch;
            *(float4*)(wp)      = z4;
            *(float4*)(wp + 4)  = z4;
            *(float4*)(wp + 8)  = z4;
            *(float4*)(wp + 12) = z4;
            if (nextok) {
                kr0 = *(const bf16x8*)(Kp + ((size_t)(fb + nk0 + sr) << 9) + (h << 6) + sc);
                kr1 = *(const bf16x8*)(Kp + ((size_t)(fb + nk0 + 32 + sr) << 9) + (h << 6) + sc);
                vr0 = *(const bf16x8*)(Vt + ((size_t)bh << 16) + ((size_t)sr << 10) + nk0 + sc);
                vr1 = *(const bf16x8*)(Vt + ((size_t)bh << 16) + ((size_t)(32 + sr) << 10) + nk0 + sc);
            }
        }
        curok = nextok;
    }
    // epilogue: attn = O + Q, plus fused stats2 partial sums
    float s1 = 0.f, s2 = 0.f;
    #pragma unroll
    for (int nt = 0; nt < 4; ++nt) {
        int d = nt * 16 + l16;
        #pragma unroll
        for (int r = 0; r < 4; ++r) {
            int q = q0 + wave * 16 + quad * 4 + r;
            size_t off = ((size_t)(fb + q) << 9) + (h << 6) + d;
            float v = accO[nt][r] + Q[off];
            attn[off] = v;
            s1 += v; s2 += v * v;
        }
    }
    #pragma unroll
    for (int o = 32; o > 0; o >>= 1) {
        s1 += __shfl_xor(s1, o);
        s2 += __shfl_xor(s2, o);
    }
    if (lane == 0) { red[wave * 2] = s1; red[wave * 2 + 1] = s2; }
    __syncthreads();
    if (t == 0) {
        atomicAdd(&stats[I_SUM2 + b], red[0] + red[2] + red[4] + red[6]);
        atomicAdd(&stats[I_SS2 + b], red[1] + red[3] + red[5] + red[7]);
    }
}

// ---------------- out = attn + relu(norm2(attn) @ Wo + bo) (dbuf) -----------
// mean2/inv2 computed per-block from raw sums (identical arithmetic).
__global__ __launch_bounds__(256) void final_gemm(
    const float* __restrict__ attn, const float* __restrict__ stats,
    const float* __restrict__ fmask, const __bf16* __restrict__ Wot,
    const float* __restrict__ bo, float* __restrict__ out)
{
    int t = threadIdx.x;
    int m0 = blockIdx.y << 6, n0 = blockIdx.x << 6;
    const int* ip = (const int*)stats;
    if (!ip[I_TMASK + (m0 >> 6)]) {
        int m = t >> 2, c = (t & 3) << 4;
        size_t base = ((size_t)(m0 + m) << 9) + n0 + c;
        #pragma unroll
        for (int i = 0; i < 4; ++i) {
            float4 a = *(const float4*)(attn + base + i * 4);
            float4 bb = *(const float4*)(bo + n0 + c + i * 4);
            float4 o;
            o.x = a.x + fmaxf(bb.x, 0.f); o.y = a.y + fmaxf(bb.y, 0.f);
            o.z = a.z + fmaxf(bb.z, 0.f); o.w = a.w + fmaxf(bb.w, 0.f);
            *(float4*)(out + base + i * 4) = o;
        }
        return;
    }
    __shared__ __align__(16) __bf16 smem[GBUF * 4];   // 2 x (As + Bs) = 20 KB
    int srow = t >> 2, skp = (t & 3) << 3;
    int arow = m0 + srow, ab = arow >> 10;
    float cntD = stats[I_CNT + ab] * 512.f;
    float mean = stats[I_SUM2 + ab] / cntD;
    float var  = stats[I_SS2 + ab] / cntD - mean * mean;
    float inv2 = rsqrtf(var + EPSV);
    float fi   = fmask[arow] * inv2;
    int wave = t >> 6, lane = t & 63, quad = lane >> 4, l16 = lane & 15;
    int aoff  = (wave * 16 + l16) * LDSTRIDE + quad * 8;
    int boff0 = l16 * LDSTRIDE + quad * 8;
    f32x4 acc[4] = {};
    const float*  Arow = attn + ((size_t)arow << 9);
    const __bf16* Brow = Wot + ((size_t)(n0 + srow) << 9);
    float4 a0 = *(const float4*)(Arow + skp);
    float4 a1 = *(const float4*)(Arow + skp + 4);
    bf16x8 bw = *(const bf16x8*)(Brow + skp);
    for (int k0 = 0; k0 < 512; k0 += 32) {
        __bf16* bb = smem + (((k0 >> 5) & 1) ? GBUF * 2 : 0);
        bf16x8 av;
        av[0] = (__bf16)((a0.x - mean) * fi); av[1] = (__bf16)((a0.y - mean) * fi);
        av[2] = (__bf16)((a0.z - mean) * fi); av[3] = (__bf16)((a0.w - mean) * fi);
        av[4] = (__bf16)((a1.x - mean) * fi); av[5] = (__bf16)((a1.y - mean) * fi);
        av[6] = (__bf16)((a1.z - mean) * fi); av[7] = (__bf16)((a1.w - mean) * fi);
        *(bf16x8*)&bb[srow * LDSTRIDE + skp] = av;
        *(bf16x8*)&bb[GBUF + srow * LDSTRIDE + skp] = bw;
        __syncthreads();
        if (k0 < 480) {
            a0 = *(const float4*)(Arow + k0 + 32 + skp);
            a1 = *(const float4*)(Arow + k0 + 36 + skp);
            bw = *(const bf16x8*)(Brow + k0 + 32 + skp);
        }
        bf16x8 af = *(const bf16x8*)&bb[aoff];
        #pragma unroll
        for (int nt = 0; nt < 4; ++nt)
            acc[nt] = MFMA16(af, *(const bf16x8*)&bb[GBUF + boff0 + nt * (16 * LDSTRIDE)], acc[nt]);
        // no trailing barrier: next iter writes the other buffer
    }
    #pragma unroll
    for (int nt = 0; nt < 4; ++nt) {
        int n = n0 + nt * 16 + l16;
        float bn = bo[n];
        #pragma unroll
        for (int reg = 0; reg < 4; ++reg) {
            int m = m0 + wave * 16 + quad * 4 + reg;
            size_t off = ((size_t)m << 9) + n;
            out[off] = attn[off] + fmaxf(acc[nt][reg] + bn, 0.f);
        }
    }
}

extern "C" void kernel_launch(void* const* d_in, const int* in_sizes, int n_in,
                              void* d_out, int out_size, void* d_ws, size_t ws_size,
                              hipStream_t stream) {
    const float* Q  = (const float*)d_in[0];
    const float* Wq = (const float*)d_in[1];
    const float* bq = (const float*)d_in[2];
    const float* Wk = (const float*)d_in[3];
    const float* bk = (const float*)d_in[4];
    const float* Wv = (const float*)d_in[5];
    const float* bv = (const float*)d_in[6];
    const float* Wo = (const float*)d_in[7];
    const float* bo = (const float*)d_in[8];
    float* out = (float*)d_out;                       // (B,S,D) = 4194304 floats
    float* w   = out + (size_t)BB * SS * DD;          // (B,H,S,S) = 67108864 floats

    char* ws = (char*)d_ws;
    float* stats  = (float*)ws;                       // 4 KB reserved (floats + tile masks)
    float* fmask  = (float*)(ws + 4096);              // 32 KB
    __bf16* Wt = (__bf16*)(ws + 4096 + 32768);        // 4 x 512x512 bf16 = 2 MB
    __bf16* Qp = Wt + ((size_t)4 << 18);              // each 8 MB
    __bf16* Kp = Qp + ((size_t)NROWS * DD);
    __bf16* Vt = Kp + ((size_t)NROWS * DD);           // [bh][64][1024] bf16 = 8 MB
    float* attn = (float*)(Vt + ((size_t)NROWS * DD)); // 16 MB fp32

    (void)hipMemsetAsync(stats, 0, 4096, stream);
    pre_k<<<NROWS + 256, 256, 0, stream>>>(Q, Wq, Wk, Wv, Wo, fmask, stats, Wt);
    projqkv_k<<<dim3(8, 128), 256, 0, stream>>>(Q, stats, fmask, Wt,
                                                bq, bk, bv, Qp, Kp, Vt);
    attn_k<<<dim3(16, 64), 256, 0, stream>>>(Qp, Kp, Vt, fmask, Q, stats, w, attn);
    final_gemm<<<dim3(8, 128), 256, 0, stream>>>(attn, stats, fmask,
                                                 Wt + ((size_t)3 << 18), bo, out);
}

// Round 8
// 568.692 us; speedup vs baseline: 1.0984x; 1.0208x over previous
//
#include <hip/hip_runtime.h>
#include <math.h>

#define BB 8
#define SS 1024
#define DD 512
#define HH 8
#define NROWS (BB*SS)          // 8192
#define EPSV 1e-5f
#define SCALE_V 0.125f          // 1/sqrt(64)

// stats[] layout (floats)
#define I_SUM1 0
#define I_SS1  8
#define I_CNT  16
#define I_SUM2 40
#define I_SS2  48
// int region (indices into (int*)stats)
#define I_TMASK 96              // 128 per-64-row-tile valid flags (atomicOr 0/1)

typedef __bf16 bf16x8 __attribute__((ext_vector_type(8)));
typedef __bf16 bf16x4 __attribute__((ext_vector_type(4)));
typedef float f32x4 __attribute__((ext_vector_type(4)));

#define MFMA16(a,b,c) __builtin_amdgcn_mfma_f32_16x16x32_bf16(a,b,c,0,0,0)

// GEMM LDS tiles: 64 rows x 32 k bf16, padded stride 40 (2-way bank alias = free)
#define LDSTRIDE 40
#define GBUF (64 * LDSTRIDE)
// attention tiles: 64 rows x 64 k bf16, padded stride 72
#define ASTR 72

// ---------------- pre pass: stats1 (blocks 0..8191) + weight transpose ------
__global__ __launch_bounds__(256) void pre_k(
    const float* __restrict__ Q,
    const float* __restrict__ Wq, const float* __restrict__ Wk,
    const float* __restrict__ Wv, const float* __restrict__ Wo,
    float* __restrict__ fmask, float* __restrict__ stats,
    __bf16* __restrict__ Wt)
{
    int bid = blockIdx.x;
    int t = threadIdx.x;
    if (bid < NROWS) {
        // ---- stats1: fmask + masked sum/sumsq per batch ----
        int row = bid;
        int b = row >> 10;
        float2 v = *(const float2*)(Q + ((size_t)row << 9) + (t << 1));
        float s  = v.x + v.y;
        float ss = v.x*v.x + v.y*v.y;
        int nz = (v.x != 0.f) || (v.y != 0.f);
        __shared__ float rs[256], rss[256];
        __shared__ int rnz[256];
        rs[t] = s; rss[t] = ss; rnz[t] = nz;
        __syncthreads();
        for (int off = 128; off > 0; off >>= 1) {
            if (t < off) { rs[t] += rs[t+off]; rss[t] += rss[t+off]; rnz[t] |= rnz[t+off]; }
            __syncthreads();
        }
        if (t == 0) {
            float f = rnz[0] ? 1.f : 0.f;
            fmask[row] = f;
            if (f != 0.f) {
                atomicAdd(&stats[I_SUM1 + b], rs[0]);
                atomicAdd(&stats[I_SS1 + b], rss[0]);
                atomicAdd(&stats[I_CNT + b], 1.f);
                atomicOr(&((int*)stats)[I_TMASK + (row >> 6)], 1);
            }
        }
        return;
    }
    // ---- weight transpose+cast: W[k][n] fp32 -> Wt[n][k] bf16 ----
    int q = bid - NROWS;
    int z = q >> 6, rem = q & 63;
    int k0 = (rem >> 3) << 6, n0 = (rem & 7) << 6;
    const float* W = (z == 0) ? Wq : (z == 1) ? Wk : (z == 2) ? Wv : Wo;
    __bf16* dst = Wt + ((size_t)z << 18);
    __shared__ float tile[64][65];
    int r = t >> 4, c = (t & 15) << 2;
    #pragma unroll
    for (int i = 0; i < 4; ++i) {
        float4 v = *(const float4*)(W + (size_t)(k0 + r + i*16) * 512 + n0 + c);
        tile[r + i*16][c+0] = v.x; tile[r + i*16][c+1] = v.y;
        tile[r + i*16][c+2] = v.z; tile[r + i*16][c+3] = v.w;
    }
    __syncthreads();
    #pragma unroll
    for (int i = 0; i < 4; ++i) {
        int n = r + i*16;
        bf16x4 o;
        o[0] = (__bf16)tile[c+0][n]; o[1] = (__bf16)tile[c+1][n];
        o[2] = (__bf16)tile[c+2][n]; o[3] = (__bf16)tile[c+3][n];
        *(bf16x4*)(dst + (size_t)(n0 + n) * 512 + k0 + c) = o;
    }
}

// ---------------- fused set_norm + QKV projection (dbuf, XCD-swizzled) ------
// 1D grid 1024. XCD swizzle: xcd = bid&7, j = bid>>3; m_blk = xcd*16 + (j>>3),
// n_blk = j&7 -> all 8 n-blocks sharing one Q-row panel land on ONE XCD's L2.
__global__ __launch_bounds__(256) void projqkv_k(
    const float* __restrict__ Q, const float* __restrict__ stats,
    const float* __restrict__ fmask, const __bf16* __restrict__ Wt,
    const float* __restrict__ bq, const float* __restrict__ bk,
    const float* __restrict__ bv,
    __bf16* __restrict__ Qp, __bf16* __restrict__ Kp, __bf16* __restrict__ Vt)
{
    __shared__ __align__(16) __bf16 smem[GBUF * 8];   // 2 x (As + 3x Bs) = 40 KB
    int t = threadIdx.x;
    int bid = blockIdx.x;
    int xcd = bid & 7, j = bid >> 3;
    int m0 = (xcd * 16 + (j >> 3)) << 6, n0 = (j & 7) << 6;
    int b = m0 >> 10, s0 = m0 & 1023, h = n0 >> 6;
    int bh = (b << 3) + h;
    const int* ip = (const int*)stats;
    if (!ip[I_TMASK + (m0 >> 6)]) {
        int m = t >> 2, ch = (t & 3) << 4;
        bf16x8 z = {};
        *(bf16x8*)(Qp + ((size_t)(m0 + m) << 9) + n0 + ch)     = z;
        *(bf16x8*)(Qp + ((size_t)(m0 + m) << 9) + n0 + ch + 8) = z;
        *(bf16x8*)(Kp + ((size_t)(m0 + m) << 9) + n0 + ch)     = z;
        *(bf16x8*)(Kp + ((size_t)(m0 + m) << 9) + n0 + ch + 8) = z;
        *(bf16x8*)(Vt + ((size_t)bh << 16) + ((size_t)m << 10) + s0 + ch)     = z;
        *(bf16x8*)(Vt + ((size_t)bh << 16) + ((size_t)m << 10) + s0 + ch + 8) = z;
        return;
    }
    int srow = t >> 2, skp = (t & 3) << 3;
    int arow = m0 + srow;
    float cntD = stats[I_CNT + b] * 512.f;
    float mean = stats[I_SUM1 + b] / cntD;
    float var  = stats[I_SS1 + b] / cntD - mean * mean;
    float inv1 = rsqrtf(var + EPSV);
    float fi   = fmask[arow] * inv1;
    int wave = t >> 6, lane = t & 63, quad = lane >> 4, l16 = lane & 15;
    int aoff  = (wave * 16 + l16) * LDSTRIDE + quad * 8;
    int boff0 = l16 * LDSTRIDE + quad * 8;
    f32x4 acc[3][4] = {};
    const float*  Arow = Q + ((size_t)arow << 9);
    const __bf16* Brow = Wt + ((size_t)(n0 + srow) << 9);
    // prefetch k0=0
    float4 a0 = *(const float4*)(Arow + skp);
    float4 a1 = *(const float4*)(Arow + skp + 4);
    bf16x8 w0 = *(const bf16x8*)(Brow + skp);
    bf16x8 w1 = *(const bf16x8*)(Brow + (1 << 18) + skp);
    bf16x8 w2 = *(const bf16x8*)(Brow + (2 << 18) + skp);
    for (int k0 = 0; k0 < 512; k0 += 32) {
        __bf16* bb = smem + (((k0 >> 5) & 1) ? GBUF * 4 : 0);
        bf16x8 av;
        av[0] = (__bf16)((a0.x - mean) * fi); av[1] = (__bf16)((a0.y - mean) * fi);
        av[2] = (__bf16)((a0.z - mean) * fi); av[3] = (__bf16)((a0.w - mean) * fi);
        av[4] = (__bf16)((a1.x - mean) * fi); av[5] = (__bf16)((a1.y - mean) * fi);
        av[6] = (__bf16)((a1.z - mean) * fi); av[7] = (__bf16)((a1.w - mean) * fi);
        *(bf16x8*)&bb[srow * LDSTRIDE + skp] = av;
        *(bf16x8*)&bb[GBUF*1 + srow * LDSTRIDE + skp] = w0;
        *(bf16x8*)&bb[GBUF*2 + srow * LDSTRIDE + skp] = w1;
        *(bf16x8*)&bb[GBUF*3 + srow * LDSTRIDE + skp] = w2;
        __syncthreads();
        if (k0 < 480) {   // prefetch next K-step; completes under MFMA
            a0 = *(const float4*)(Arow + k0 + 32 + skp);
            a1 = *(const float4*)(Arow + k0 + 36 + skp);
            w0 = *(const bf16x8*)(Brow + k0 + 32 + skp);
            w1 = *(const bf16x8*)(Brow + (1 << 18) + k0 + 32 + skp);
            w2 = *(const bf16x8*)(Brow + (2 << 18) + k0 + 32 + skp);
        }
        bf16x8 af = *(const bf16x8*)&bb[aoff];
        #pragma unroll
        for (int nt = 0; nt < 4; ++nt) {
            int bo = boff0 + nt * (16 * LDSTRIDE);
            acc[0][nt] = MFMA16(af, *(const bf16x8*)&bb[GBUF*1 + bo], acc[0][nt]);
            acc[1][nt] = MFMA16(af, *(const bf16x8*)&bb[GBUF*2 + bo], acc[1][nt]);
            acc[2][nt] = MFMA16(af, *(const bf16x8*)&bb[GBUF*3 + bo], acc[2][nt]);
        }
        // no trailing barrier: next iter writes the other buffer
    }
    float fmr[4];
    #pragma unroll
    for (int reg = 0; reg < 4; ++reg) fmr[reg] = fmask[m0 + wave*16 + quad*4 + reg];
    __bf16* Cs = smem;    // buffer0 region; last loop reads were buffer1
    #pragma unroll
    for (int z = 0; z < 2; ++z) {
        const float* bias = z ? bk : bq;
        __bf16* C = z ? Kp : Qp;
        #pragma unroll
        for (int nt = 0; nt < 4; ++nt) {
            float bn = bias[n0 + nt * 16 + l16];
            #pragma unroll
            for (int reg = 0; reg < 4; ++reg) {
                int m = wave * 16 + quad * 4 + reg;
                Cs[m * 70 + nt * 16 + l16] = (__bf16)((acc[z][nt][reg] + bn) * fmr[reg]);
            }
        }
        __syncthreads();
        int m = t >> 2, ch = (t & 3) << 4;
        bf16x8 o0 = *(const bf16x8*)&Cs[m * 70 + ch];
        bf16x8 o1 = *(const bf16x8*)&Cs[m * 70 + ch + 8];
        *(bf16x8*)(C + ((size_t)(m0 + m) << 9) + n0 + ch)     = o0;
        *(bf16x8*)(C + ((size_t)(m0 + m) << 9) + n0 + ch + 8) = o1;
        __syncthreads();
    }
    // z=2: store transposed into Cs ([d][s]) then coalesced Vt write
    #pragma unroll
    for (int nt = 0; nt < 4; ++nt) {
        int d = nt * 16 + l16;
        float bn = bv[n0 + d];
        #pragma unroll
        for (int reg = 0; reg < 4; ++reg) {
            int sl = wave * 16 + quad * 4 + reg;
            Cs[d * 70 + sl] = (__bf16)((acc[2][nt][reg] + bn) * fmr[reg]);
        }
    }
    __syncthreads();
    {
        int d = t >> 2, seg = (t & 3) << 4;
        bf16x8 o0 = *(const bf16x8*)&Cs[d * 70 + seg];
        bf16x8 o1 = *(const bf16x8*)&Cs[d * 70 + seg + 8];
        *(bf16x8*)(Vt + ((size_t)bh << 16) + ((size_t)d << 10) + s0 + seg)     = o0;
        *(bf16x8*)(Vt + ((size_t)bh << 16) + ((size_t)d << 10) + s0 + seg + 8) = o1;
    }
}

// ---------------- fused attention: rowsum (A) + attn (B), XCD-swizzled ------
// 1D grid 1024. xcd = bid&7, j = bid>>3; bh = xcd*8 + (j>>4), q_blk = j&15
// -> all 16 q-blocks sharing one bh's K/V land on ONE XCD's L2.
__global__ __launch_bounds__(256) void attn_k(
    const __bf16* __restrict__ Qp, const __bf16* __restrict__ Kp,
    const __bf16* __restrict__ Vt,
    const float* __restrict__ fmask, const float* __restrict__ Q,
    float* __restrict__ stats, float* __restrict__ w, float* __restrict__ attn)
{
    int bid = blockIdx.x;
    int xcd = bid & 7, j = bid >> 3;
    int bh = xcd * 8 + (j >> 4);
    int q0 = (j & 15) << 6;
    int b = bh >> 3, h = bh & 7;
    int t = threadIdx.x;
    const int* ip = (const int*)stats;
    const int* tm = ip + I_TMASK + (b << 4);
    int kb = 0;
    #pragma unroll
    for (int i = 0; i < 16; ++i) kb |= (tm[i] ? 1 : 0) << i;
    int fb = b << 10;
    size_t wqbase = ((size_t)bh << 20) + ((size_t)q0 << 10);
    if (!((kb >> (q0 >> 6)) & 1)) {
        // fully-masked q tile: w rows = 0, attn = Q; stats contribution 0
        int q = t >> 2, ch = (t & 3) << 4;
        float4 z4 = {0.f, 0.f, 0.f, 0.f};
        float* wp0 = w + wqbase + ((size_t)q << 10) + ch;
        #pragma unroll
        for (int kc0 = 0; kc0 < 1024; kc0 += 64) {
            *(float4*)(wp0 + kc0)      = z4;
            *(float4*)(wp0 + kc0 + 4)  = z4;
            *(float4*)(wp0 + kc0 + 8)  = z4;
            *(float4*)(wp0 + kc0 + 12) = z4;
        }
        size_t base = ((size_t)(fb + q0 + q) << 9) + (h << 6) + ch;
        #pragma unroll
        for (int i = 0; i < 4; ++i)
            *(float4*)(attn + base + i*4) = *(const float4*)(Q + base + i*4);
        return;
    }
    __shared__ __align__(16) __bf16 Ks[64 * ASTR];
    __shared__ __align__(16) __bf16 Vs[64 * ASTR];
    __shared__ __align__(16) __bf16 Ws[64 * ASTR];
    __shared__ float red[8];
    int wave = t >> 6, lane = t & 63, quad = lane >> 4, l16 = lane & 15;
    int sr = t >> 3, sc = (t & 7) << 3;
    // Q fragments: one-time direct gather
    const __bf16* Qr = Qp + ((size_t)(fb + q0 + wave*16 + l16) << 9) + (h << 6) + (quad << 3);
    bf16x8 qa0 = *(const bf16x8*)(Qr);
    bf16x8 qa1 = *(const bf16x8*)(Qr + 32);
    int aoff = (wave * 16 + l16) * ASTR + (quad << 3);

    // ---- phase A: row sums ----
    float rsum[4] = {0.f, 0.f, 0.f, 0.f};
    bf16x8 kr0, kr1;
    bool curok = kb & 1;
    if (curok) {
        kr0 = *(const bf16x8*)(Kp + ((size_t)(fb + sr) << 9) + (h << 6) + sc);
        kr1 = *(const bf16x8*)(Kp + ((size_t)(fb + 32 + sr) << 9) + (h << 6) + sc);
    }
    for (int kc = 0; kc < 16; ++kc) {
        bool nextok = (kc < 15) && ((kb >> (kc + 1)) & 1);
        int nbase = fb + ((kc + 1) << 6);
        if (curok) {
            *(bf16x8*)&Ks[sr * ASTR + sc] = kr0;
            *(bf16x8*)&Ks[(32 + sr) * ASTR + sc] = kr1;
            __syncthreads();
            if (nextok) {
                kr0 = *(const bf16x8*)(Kp + ((size_t)(nbase + sr) << 9) + (h << 6) + sc);
                kr1 = *(const bf16x8*)(Kp + ((size_t)(nbase + 32 + sr) << 9) + (h << 6) + sc);
            }
            int kc0 = kc << 6;
            #pragma unroll
            for (int nt = 0; nt < 4; ++nt) {
                int boff = (nt * 16 + l16) * ASTR + (quad << 3);
                f32x4 s = {};
                s = MFMA16(qa0, *(const bf16x8*)&Ks[boff], s);
                s = MFMA16(qa1, *(const bf16x8*)&Ks[boff + 32], s);
                float fk = fmask[fb + kc0 + nt * 16 + l16];
                #pragma unroll
                for (int r = 0; r < 4; ++r)
                    rsum[r] += (fk != 0.f) ? __expf(s[r] * SCALE_V) : 0.f;
            }
            __syncthreads();
        } else if (nextok) {
            kr0 = *(const bf16x8*)(Kp + ((size_t)(nbase + sr) << 9) + (h << 6) + sc);
            kr1 = *(const bf16x8*)(Kp + ((size_t)(nbase + 32 + sr) << 9) + (h << 6) + sc);
        }
        curok = nextok;
    }
    float inv[4];
    #pragma unroll
    for (int r = 0; r < 4; ++r) {
        float v = rsum[r];
        v += __shfl_xor(v, 1); v += __shfl_xor(v, 2);
        v += __shfl_xor(v, 4); v += __shfl_xor(v, 8);
        float fq = fmask[fb + q0 + wave * 16 + quad * 4 + r];
        inv[r] = (fq != 0.f && v > 0.f) ? 1.f / v : 0.f;
    }

    // ---- phase B: attention ----
    f32x4 accO[4] = {};
    bf16x8 vr0, vr1;
    curok = kb & 1;
    if (curok) {
        kr0 = *(const bf16x8*)(Kp + ((size_t)(fb + sr) << 9) + (h << 6) + sc);
        kr1 = *(const bf16x8*)(Kp + ((size_t)(fb + 32 + sr) << 9) + (h << 6) + sc);
        vr0 = *(const bf16x8*)(Vt + ((size_t)bh << 16) + ((size_t)sr << 10) + sc);
        vr1 = *(const bf16x8*)(Vt + ((size_t)bh << 16) + ((size_t)(32 + sr) << 10) + sc);
    }
    for (int kc = 0; kc < 16; ++kc) {
        int kc0 = kc << 6;
        bool nextok = (kc < 15) && ((kb >> (kc + 1)) & 1);
        int nk0 = kc0 + 64;
        if (curok) {
            *(bf16x8*)&Ks[sr * ASTR + sc] = kr0;
            *(bf16x8*)&Ks[(32 + sr) * ASTR + sc] = kr1;
            *(bf16x8*)&Vs[sr * ASTR + sc] = vr0;
            *(bf16x8*)&Vs[(32 + sr) * ASTR + sc] = vr1;
            __syncthreads();
            if (nextok) {   // prefetch next K/V tile under QK^T+PV compute
                kr0 = *(const bf16x8*)(Kp + ((size_t)(fb + nk0 + sr) << 9) + (h << 6) + sc);
                kr1 = *(const bf16x8*)(Kp + ((size_t)(fb + nk0 + 32 + sr) << 9) + (h << 6) + sc);
                vr0 = *(const bf16x8*)(Vt + ((size_t)bh << 16) + ((size_t)sr << 10) + nk0 + sc);
                vr1 = *(const bf16x8*)(Vt + ((size_t)bh << 16) + ((size_t)(32 + sr) << 10) + nk0 + sc);
            }
            #pragma unroll
            for (int nt = 0; nt < 4; ++nt) {
                int boff = (nt * 16 + l16) * ASTR + (quad << 3);
                f32x4 s = {};
                s = MFMA16(qa0, *(const bf16x8*)&Ks[boff], s);
                s = MFMA16(qa1, *(const bf16x8*)&Ks[boff + 32], s);
                float fk = fmask[fb + kc0 + nt * 16 + l16];
                #pragma unroll
                for (int r = 0; r < 4; ++r) {
                    float p = (fk != 0.f) ? __expf(s[r] * SCALE_V) * inv[r] : 0.f;
                    Ws[(wave * 16 + quad * 4 + r) * ASTR + nt * 16 + l16] = (__bf16)p;
                }
            }
            __syncthreads();
            bf16x8 pa0 = *(const bf16x8*)&Ws[aoff];
            bf16x8 pa1 = *(const bf16x8*)&Ws[aoff + 32];
            #pragma unroll
            for (int nt = 0; nt < 4; ++nt) {
                int boff = (nt * 16 + l16) * ASTR + (quad << 3);
                accO[nt] = MFMA16(pa0, *(const bf16x8*)&Vs[boff], accO[nt]);
                accO[nt] = MFMA16(pa1, *(const bf16x8*)&Vs[boff + 32], accO[nt]);
            }
            {
                int q = t >> 2, ch = (t & 3) << 4;
                bf16x8 w0 = *(const bf16x8*)&Ws[q * ASTR + ch];
                bf16x8 w1 = *(const bf16x8*)&Ws[q * ASTR + ch + 8];
                float4 f0, f1, f2, f3;
                f0.x = (float)w0[0]; f0.y = (float)w0[1]; f0.z = (float)w0[2]; f0.w = (float)w0[3];
                f1.x = (float)w0[4]; f1.y = (float)w0[5]; f1.z = (float)w0[6]; f1.w = (float)w0[7];
                f2.x = (float)w1[0]; f2.y = (float)w1[1]; f2.z = (float)w1[2]; f2.w = (float)w1[3];
                f3.x = (float)w1[4]; f3.y = (float)w1[5]; f3.z = (float)w1[6]; f3.w = (float)w1[7];
                float* wp = w + wqbase + ((size_t)q << 10) + kc0 + ch;
                *(float4*)(wp)      = f0;
                *(float4*)(wp + 4)  = f1;
                *(float4*)(wp + 8)  = f2;
                *(float4*)(wp + 12) = f3;
            }
            __syncthreads();
        } else {
            // masked k tile: w columns are exact zeros, no compute
            int q = t >> 2, ch = (t & 3) << 4;
            float4 z4 = {0.f, 0.f, 0.f, 0.f};
            float* wp = w + wqbase + ((size_t)q << 10) + kc0 + ch;
            *(float4*)(wp)      = z4;
            *(float4*)(wp + 4)  = z4;
            *(float4*)(wp + 8)  = z4;
            *(float4*)(wp + 12) = z4;
            if (nextok) {
                kr0 = *(const bf16x8*)(Kp + ((size_t)(fb + nk0 + sr) << 9) + (h << 6) + sc);
                kr1 = *(const bf16x8*)(Kp + ((size_t)(fb + nk0 + 32 + sr) << 9) + (h << 6) + sc);
                vr0 = *(const bf16x8*)(Vt + ((size_t)bh << 16) + ((size_t)sr << 10) + nk0 + sc);
                vr1 = *(const bf16x8*)(Vt + ((size_t)bh << 16) + ((size_t)(32 + sr) << 10) + nk0 + sc);
            }
        }
        curok = nextok;
    }
    // epilogue: attn = O + Q, plus fused stats2 partial sums
    float s1 = 0.f, s2 = 0.f;
    #pragma unroll
    for (int nt = 0; nt < 4; ++nt) {
        int d = nt * 16 + l16;
        #pragma unroll
        for (int r = 0; r < 4; ++r) {
            int q = q0 + wave * 16 + quad * 4 + r;
            size_t off = ((size_t)(fb + q) << 9) + (h << 6) + d;
            float v = accO[nt][r] + Q[off];
            attn[off] = v;
            s1 += v; s2 += v * v;
        }
    }
    #pragma unroll
    for (int o = 32; o > 0; o >>= 1) {
        s1 += __shfl_xor(s1, o);
        s2 += __shfl_xor(s2, o);
    }
    if (lane == 0) { red[wave * 2] = s1; red[wave * 2 + 1] = s2; }
    __syncthreads();
    if (t == 0) {
        atomicAdd(&stats[I_SUM2 + b], red[0] + red[2] + red[4] + red[6]);
        atomicAdd(&stats[I_SS2 + b], red[1] + red[3] + red[5] + red[7]);
    }
}

// ---------------- out = attn + relu(norm2(attn) @ Wo + bo), XCD-swizzled ----
__global__ __launch_bounds__(256) void final_gemm(
    const float* __restrict__ attn, const float* __restrict__ stats,
    const float* __restrict__ fmask, const __bf16* __restrict__ Wot,
    const float* __restrict__ bo, float* __restrict__ out)
{
    int t = threadIdx.x;
    int bid = blockIdx.x;
    int xcd = bid & 7, j = bid >> 3;
    int m0 = (xcd * 16 + (j >> 3)) << 6, n0 = (j & 7) << 6;
    const int* ip = (const int*)stats;
    if (!ip[I_TMASK + (m0 >> 6)]) {
        int m = t >> 2, c = (t & 3) << 4;
        size_t base = ((size_t)(m0 + m) << 9) + n0 + c;
        #pragma unroll
        for (int i = 0; i < 4; ++i) {
            float4 a = *(const float4*)(attn + base + i * 4);
            float4 bb = *(const float4*)(bo + n0 + c + i * 4);
            float4 o;
            o.x = a.x + fmaxf(bb.x, 0.f); o.y = a.y + fmaxf(bb.y, 0.f);
            o.z = a.z + fmaxf(bb.z, 0.f); o.w = a.w + fmaxf(bb.w, 0.f);
            *(float4*)(out + base + i * 4) = o;
        }
        return;
    }
    __shared__ __align__(16) __bf16 smem[GBUF * 4];   // 2 x (As + Bs) = 20 KB
    int srow = t >> 2, skp = (t & 3) << 3;
    int arow = m0 + srow, ab = arow >> 10;
    float cntD = stats[I_CNT + ab] * 512.f;
    float mean = stats[I_SUM2 + ab] / cntD;
    float var  = stats[I_SS2 + ab] / cntD - mean * mean;
    float inv2 = rsqrtf(var + EPSV);
    float fi   = fmask[arow] * inv2;
    int wave = t >> 6, lane = t & 63, quad = lane >> 4, l16 = lane & 15;
    int aoff  = (wave * 16 + l16) * LDSTRIDE + quad * 8;
    int boff0 = l16 * LDSTRIDE + quad * 8;
    f32x4 acc[4] = {};
    const float*  Arow = attn + ((size_t)arow << 9);
    const __bf16* Brow = Wot + ((size_t)(n0 + srow) << 9);
    float4 a0 = *(const float4*)(Arow + skp);
    float4 a1 = *(const float4*)(Arow + skp + 4);
    bf16x8 bw = *(const bf16x8*)(Brow + skp);
    for (int k0 = 0; k0 < 512; k0 += 32) {
        __bf16* bb = smem + (((k0 >> 5) & 1) ? GBUF * 2 : 0);
        bf16x8 av;
        av[0] = (__bf16)((a0.x - mean) * fi); av[1] = (__bf16)((a0.y - mean) * fi);
        av[2] = (__bf16)((a0.z - mean) * fi); av[3] = (__bf16)((a0.w - mean) * fi);
        av[4] = (__bf16)((a1.x - mean) * fi); av[5] = (__bf16)((a1.y - mean) * fi);
        av[6] = (__bf16)((a1.z - mean) * fi); av[7] = (__bf16)((a1.w - mean) * fi);
        *(bf16x8*)&bb[srow * LDSTRIDE + skp] = av;
        *(bf16x8*)&bb[GBUF + srow * LDSTRIDE + skp] = bw;
        __syncthreads();
        if (k0 < 480) {
            a0 = *(const float4*)(Arow + k0 + 32 + skp);
            a1 = *(const float4*)(Arow + k0 + 36 + skp);
            bw = *(const bf16x8*)(Brow + k0 + 32 + skp);
        }
        bf16x8 af = *(const bf16x8*)&bb[aoff];
        #pragma unroll
        for (int nt = 0; nt < 4; ++nt)
            acc[nt] = MFMA16(af, *(const bf16x8*)&bb[GBUF + boff0 + nt * (16 * LDSTRIDE)], acc[nt]);
        // no trailing barrier: next iter writes the other buffer
    }
    #pragma unroll
    for (int nt = 0; nt < 4; ++nt) {
        int n = n0 + nt * 16 + l16;
        float bn = bo[n];
        #pragma unroll
        for (int reg = 0; reg < 4; ++reg) {
            int m = m0 + wave * 16 + quad * 4 + reg;
            size_t off = ((size_t)m << 9) + n;
            out[off] = attn[off] + fmaxf(acc[nt][reg] + bn, 0.f);
        }
    }
}

extern "C" void kernel_launch(void* const* d_in, const int* in_sizes, int n_in,
                              void* d_out, int out_size, void* d_ws, size_t ws_size,
                              hipStream_t stream) {
    const float* Q  = (const float*)d_in[0];
    const float* Wq = (const float*)d_in[1];
    const float* bq = (const float*)d_in[2];
    const float* Wk = (const float*)d_in[3];
    const float* bk = (const float*)d_in[4];
    const float* Wv = (const float*)d_in[5];
    const float* bv = (const float*)d_in[6];
    const float* Wo = (const float*)d_in[7];
    const float* bo = (const float*)d_in[8];
    float* out = (float*)d_out;                       // (B,S,D) = 4194304 floats
    float* w   = out + (size_t)BB * SS * DD;          // (B,H,S,S) = 67108864 floats

    char* ws = (char*)d_ws;
    float* stats  = (float*)ws;                       // 4 KB reserved (floats + tile masks)
    float* fmask  = (float*)(ws + 4096);              // 32 KB
    __bf16* Wt = (__bf16*)(ws + 4096 + 32768);        // 4 x 512x512 bf16 = 2 MB
    __bf16* Qp = Wt + ((size_t)4 << 18);              // each 8 MB
    __bf16* Kp = Qp + ((size_t)NROWS * DD);
    __bf16* Vt = Kp + ((size_t)NROWS * DD);           // [bh][64][1024] bf16 = 8 MB
    float* attn = (float*)(Vt + ((size_t)NROWS * DD)); // 16 MB fp32

    (void)hipMemsetAsync(stats, 0, 4096, stream);
    pre_k<<<NROWS + 256, 256, 0, stream>>>(Q, Wq, Wk, Wv, Wo, fmask, stats, Wt);
    projqkv_k<<<1024, 256, 0, stream>>>(Q, stats, fmask, Wt,
                                        bq, bk, bv, Qp, Kp, Vt);
    attn_k<<<1024, 256, 0, stream>>>(Qp, Kp, Vt, fmask, Q, stats, w, attn);
    final_gemm<<<1024, 256, 0, stream>>>(attn, stats, fmask,
                                         Wt + ((size_t)3 << 18), bo, out);
}